// Round 6
// baseline (558.054 us; speedup 1.0000x reference)
//
#include <hip/hip_runtime.h>

#define B_    32
#define C_    256
#define HWI   4096   // 64*64
#define HDIM  64
#define NW    65536  // elems per weight matrix (256x256)
#define SHIFT 20.0f  // fixed softmax shift

typedef short short8 __attribute__((ext_vector_type(8)));
typedef short s4v    __attribute__((ext_vector_type(4)));
typedef float f32x4  __attribute__((ext_vector_type(4)));

// split fp32 -> bf16 hi (RNE) + bf16 lo (RNE of remainder)
__device__ __forceinline__ void f2bf_pair(float x, short& h, short& l) {
    unsigned u = __float_as_uint(x);
    unsigned r = u + 0x7FFFu + ((u >> 16) & 1u);
    unsigned short hb = (unsigned short)(r >> 16);
    float hf = __uint_as_float((unsigned)hb << 16);
    float d = x - hf;
    unsigned v = __float_as_uint(d);
    unsigned r2 = v + 0x7FFFu + ((v >> 16) & 1u);
    h = (short)hb;
    l = (short)(r2 >> 16);
}

__device__ __forceinline__ unsigned short f2bf(float x) {
    unsigned u = __float_as_uint(x);
    return (unsigned short)((u + 0x7FFFu + ((u >> 16) & 1u)) >> 16);
}
__device__ __forceinline__ float bf2f(unsigned short b) {
    return __uint_as_float((unsigned)b << 16);
}

// ---------------------------------------------------------------------------
// Pre-split weights [256x256] fp32 -> bf16 hi/lo, MFMA-fragment-linear:
// flat = (o>>4)*4096 + (k>>3)*128 + (o&15)*8 + (k&7)
// ---------------------------------------------------------------------------
__global__ __launch_bounds__(256)
void wsplit_k(const float* __restrict__ w, short* __restrict__ wh,
              short* __restrict__ wl)
{
    const int g  = blockIdx.x * 256 + threadIdx.x;
    const int o  = g >> 5, k8 = g & 31;
    const float* src = w + o * 256 + k8 * 8;
    const int dst = (o >> 4) * 4096 + k8 * 128 + (o & 15) * 8;
    short8 h8, l8;
    #pragma unroll
    for (int j = 0; j < 8; ++j) { short h, l; f2bf_pair(src[j], h, l); h8[j] = h; l8[j] = l; }
    *(short8*)(wh + dst) = h8;
    *(short8*)(wl + dst) = l8;
}

// ---------------------------------------------------------------------------
// building blocks
// ---------------------------------------------------------------------------
__device__ __forceinline__ void stage_load(const float* __restrict__ inb,
                                           int half, int sp, int kq, float* v)
{
    #pragma unroll
    for (int r = 0; r < 4; ++r) {
        const int k8 = half * 16 + r * 4 + kq;
        const float* gx = inb + (size_t)(k8 * 8) * HWI + sp;
        #pragma unroll
        for (int j = 0; j < 8; ++j) v[r * 8 + j] = gx[(size_t)j * HWI];
    }
}

__device__ __forceinline__ void stage_write(int half, int sp, int kq,
        const float* v, short (*xh)[256], short (*xl)[256])
{
    #pragma unroll
    for (int r = 0; r < 4; ++r) {
        const int k8 = half * 16 + r * 4 + kq;
        short8 h8, l8;
        #pragma unroll
        for (int j = 0; j < 8; ++j) {
            short h, l; f2bf_pair(v[r * 8 + j], h, l); h8[j] = h; l8[j] = l;
        }
        const int ch = (k8 ^ (sp & 7)) * 8;
        *(short8*)&xh[sp][ch] = h8;
        *(short8*)&xl[sp][ch] = l8;
    }
}

// A-frags (weights) for (cv, s): a[0..3]=hi, a[4..7]=lo
__device__ __forceinline__ void load_a(short8 a[8], const short* __restrict__ wb,
                                       int cv, int s, int lane, int o16b)
{
    const short* wh = wb + (size_t)cv * 2 * NW;
    const short* wl = wh + NW;
    const int k8 = s * 4 + (lane >> 4);
    #pragma unroll
    for (int i = 0; i < 4; ++i) {
        const int aoff = ((o16b + i) * 32 + k8) * 128 + (lane & 15) * 8;
        a[i]     = *(const short8*)(wh + aoff);
        a[4 + i] = *(const short8*)(wl + aoff);
    }
}

// B-frags (x) for step s from LDS: b[0..3]=hi, b[4..7]=lo
__device__ __forceinline__ void load_b(short8 b[8], int s, int lane,
        const short (*xh)[256], const short (*xl)[256])
{
    const int k8 = s * 4 + (lane >> 4);
    #pragma unroll
    for (int f = 0; f < 4; ++f) {
        const int pr = f * 16 + (lane & 15);
        const int ch = (k8 ^ (pr & 7)) * 8;
        b[f]     = *(const short8*)&xh[pr][ch];
        b[4 + f] = *(const short8*)&xl[pr][ch];
    }
}

__device__ __forceinline__ void mfma3(const short8 a[8], const short8 b[8],
                                      f32x4 acc[4][4])
{
    #pragma unroll
    for (int i = 0; i < 4; ++i)
        #pragma unroll
        for (int f = 0; f < 4; ++f) {
            acc[i][f] = __builtin_amdgcn_mfma_f32_16x16x32_bf16(a[i],     b[f],     acc[i][f], 0, 0, 0);
            acc[i][f] = __builtin_amdgcn_mfma_f32_16x16x32_bf16(a[4 + i], b[f],     acc[i][f], 0, 0, 0);
            acc[i][f] = __builtin_amdgcn_mfma_f32_16x16x32_bf16(a[i],     b[4 + f], acc[i][f], 0, 0, 0);
        }
}

__device__ __forceinline__ void conv_epi_f32(const f32x4 acc[4][4],
        const float* __restrict__ bias, float* __restrict__ ob,
        int p0, int wv, int lane)
{
    const int pl = p0 + (lane & 15);
    #pragma unroll
    for (int i = 0; i < 4; ++i)
        #pragma unroll
        for (int r = 0; r < 4; ++r) {
            const int o = wv * 64 + i * 16 + (lane >> 4) * 4 + r;
            const float bz = bias[o];
            #pragma unroll
            for (int f = 0; f < 4; ++f)
                ob[(size_t)o * HWI + pl + f * 16] = acc[i][f][r] + bz;
        }
}

__device__ __forceinline__ void conv_epi_bf16(const f32x4 acc[4][4],
        const float* __restrict__ bias, unsigned short* __restrict__ ob,
        int p0, int wv, int lane)
{
    const int pl = p0 + (lane & 15);
    #pragma unroll
    for (int i = 0; i < 4; ++i)
        #pragma unroll
        for (int r = 0; r < 4; ++r) {
            const int o = wv * 64 + i * 16 + (lane >> 4) * 4 + r;
            const float bz = bias[o];
            #pragma unroll
            for (int f = 0; f < 4; ++f)
                ob[(size_t)o * HWI + pl + f * 16] = f2bf(acc[i][f][r] + bz);
        }
}

// pipeline step: issue next A-frag loads, then LDS B reads, then MFMA
#define CSTEP(Acur, Anext, cvn, sn, s, accv)                 \
    load_a(Anext, wb, cvn, sn, lane, o16b);                  \
    load_b(Bf, s, lane, xh, xl);                             \
    mfma3(Acur, Bf, accv);

// ---------------------------------------------------------------------------
// Fused 1x1 convs (fp32 in, bf16x3 MFMA), A-frag double-buffered pipeline.
// Block = 256 thr (4 waves), p-tile 64, K=256 staged in LDS in two halves.
// XCD-chunked swizzle. Last output bf16 when G1B. grid: (HWI/64, B_)
// ---------------------------------------------------------------------------
template<int NOUT, bool G1B>
__global__ __launch_bounds__(256)
void convN_k(const float* __restrict__ in, const short* __restrict__ wb,
             const float* __restrict__ b0, const float* __restrict__ b1,
             const float* __restrict__ b2,
             void* o0, void* o1, void* o2)
{
    __shared__ short xh[64][256];
    __shared__ short xl[64][256];

    const int tid  = threadIdx.x;
    const int lane = tid & 63;
    const int wv   = tid >> 6;

    const int id    = blockIdx.y * gridDim.x + blockIdx.x;
    const int chunk = (gridDim.x * gridDim.y) >> 3;
    const int nid   = (id & 7) * chunk + (id >> 3);
    const int p0    = (nid & 63) * 64;
    const int b     = nid >> 6;

    const float* inb = in + (size_t)b * C_ * HWI + p0;
    const int sp = tid & 63, kq = tid >> 6;
    const int o16b = wv * 4;
    const size_t obase = (size_t)b * C_ * HWI;

    short8 A0[8], A1[8], Bf[8];

    load_a(A0, wb, 0, 0, lane, o16b);      // earliest possible prefetch

    float v[32];
    stage_load(inb, 0, sp, kq, v);
    stage_write(0, sp, kq, v, xh, xl);
    __syncthreads();

    stage_load(inb, 1, sp, kq, v);         // x half-1 loads in flight

    f32x4 acc[4][4] = {};
    CSTEP(A0, A1, 0, 1, 0, acc)
    CSTEP(A1, A0, 0, 2, 1, acc)
    CSTEP(A0, A1, 0, 3, 2, acc)
    CSTEP(A1, A0, 0, 4, 3, acc)            // prefetch s=4 across the barrier

    stage_write(1, sp, kq, v, xh, xl);
    __syncthreads();

    CSTEP(A0, A1, 0, 5, 4, acc)
    CSTEP(A1, A0, 0, 6, 5, acc)
    CSTEP(A0, A1, 0, 7, 6, acc)
    // last step of cv0: prefetch cv1 (or harmless (0,0) when NOUT==1)
    if (NOUT > 1) { CSTEP(A1, A0, 1, 0, 7, acc) }
    else          { CSTEP(A1, A0, 0, 0, 7, acc) }

    if (G1B && NOUT == 1)
        conv_epi_bf16(acc, b0, (unsigned short*)o0 + obase, p0, wv, lane);
    else
        conv_epi_f32(acc, b0, (float*)o0 + obase, p0, wv, lane);

    if (NOUT > 1) {
        f32x4 acc2[4][4] = {};
        CSTEP(A0, A1, 1, 1, 0, acc2)
        CSTEP(A1, A0, 1, 2, 1, acc2)
        CSTEP(A0, A1, 1, 3, 2, acc2)
        CSTEP(A1, A0, 1, 4, 3, acc2)
        CSTEP(A0, A1, 1, 5, 4, acc2)
        CSTEP(A1, A0, 1, 6, 5, acc2)
        CSTEP(A0, A1, 1, 7, 6, acc2)
        if (NOUT > 2) { CSTEP(A1, A0, 2, 0, 7, acc2) }
        else          { CSTEP(A1, A0, 0, 0, 7, acc2) }

        if (G1B && NOUT == 2)
            conv_epi_bf16(acc2, b1, (unsigned short*)o1 + obase, p0, wv, lane);
        else
            conv_epi_f32(acc2, b1, (float*)o1 + obase, p0, wv, lane);
    }

    if (NOUT > 2) {
        f32x4 acc3[4][4] = {};
        CSTEP(A0, A1, 2, 1, 0, acc3)
        CSTEP(A1, A0, 2, 2, 1, acc3)
        CSTEP(A0, A1, 2, 3, 2, acc3)
        CSTEP(A1, A0, 2, 4, 3, acc3)
        CSTEP(A0, A1, 2, 5, 4, acc3)
        CSTEP(A1, A0, 2, 6, 5, acc3)
        CSTEP(A0, A1, 2, 7, 6, acc3)
        CSTEP(A1, A0, 0, 0, 7, acc3)      // tail prefetch harmless

        if (G1B)
            conv_epi_bf16(acc3, b2, (unsigned short*)o2 + obase, p0, wv, lane);
        else
            conv_epi_f32(acc3, b2, (float*)o2 + obase, p0, wv, lane);
    }
}

// ---------------------------------------------------------------------------
// Final conv: bf16 input, 2-term MFMA, A-frag double-buffered pipeline,
// +bias +residual -> fp32. 32 KB LDS. grid: (HWI/64, B_)
// ---------------------------------------------------------------------------
__device__ __forceinline__ void load_a2(short8 a[8], const short* __restrict__ wh,
                                        const short* __restrict__ wl,
                                        int s, int lane, int o16b)
{
    const int k8 = s * 4 + (lane >> 4);
    #pragma unroll
    for (int i = 0; i < 4; ++i) {
        const int aoff = ((o16b + i) * 32 + k8) * 128 + (lane & 15) * 8;
        a[i]     = *(const short8*)(wh + aoff);
        a[4 + i] = *(const short8*)(wl + aoff);
    }
}

__device__ __forceinline__ void mfma2y(const short8 a[8], const short8 bq[4],
                                       f32x4 acc[4][4])
{
    #pragma unroll
    for (int i = 0; i < 4; ++i)
        #pragma unroll
        for (int f = 0; f < 4; ++f) {
            acc[i][f] = __builtin_amdgcn_mfma_f32_16x16x32_bf16(a[i],     bq[f], acc[i][f], 0, 0, 0);
            acc[i][f] = __builtin_amdgcn_mfma_f32_16x16x32_bf16(a[4 + i], bq[f], acc[i][f], 0, 0, 0);
        }
}

#define YSTEP(Acur, Anext, sn, s, accv)                       \
    load_a2(Anext, wh, wl, sn, lane, o16b);                   \
    { const int k8y = (s) * 4 + (lane >> 4);                  \
      _Pragma("unroll")                                       \
      for (int f = 0; f < 4; ++f) {                           \
          const int pr = f * 16 + (lane & 15);                \
          Bq[f] = *(const short8*)&ys[pr][(k8y ^ (pr & 7)) * 8]; } } \
    mfma2y(Acur, Bq, accv);

__global__ __launch_bounds__(256, 3)
void convY_k(const unsigned short* __restrict__ in, const float* __restrict__ res,
             const short* __restrict__ wh, const short* __restrict__ wl,
             const float* __restrict__ bias, float* __restrict__ out)
{
    __shared__ short ys[64][256];   // 32 KB

    const int tid  = threadIdx.x;
    const int lane = tid & 63;
    const int wv   = tid >> 6;

    const int id    = blockIdx.y * gridDim.x + blockIdx.x;
    const int chunk = (gridDim.x * gridDim.y) >> 3;
    const int nid   = (id & 7) * chunk + (id >> 3);
    const int p0    = (nid & 63) * 64;
    const int b     = nid >> 6;

    const unsigned short* inb = in + (size_t)b * C_ * HWI + p0;
    const int sp = tid & 63, kq = tid >> 6;
    const int o16b = wv * 4;

    short8 A0[8], A1[8], Bq[4];
    load_a2(A0, wh, wl, 0, lane, o16b);

    unsigned short uv[32];
    #pragma unroll
    for (int r = 0; r < 4; ++r) {
        const int k8 = r * 4 + kq;
        #pragma unroll
        for (int j = 0; j < 8; ++j) uv[r * 8 + j] = inb[(size_t)(k8 * 8 + j) * HWI + sp];
    }
    #pragma unroll
    for (int r = 0; r < 4; ++r) {
        const int k8 = r * 4 + kq;
        short8 v8;
        #pragma unroll
        for (int j = 0; j < 8; ++j) v8[j] = (short)uv[r * 8 + j];
        *(short8*)&ys[sp][(k8 ^ (sp & 7)) * 8] = v8;
    }
    __syncthreads();

    // half-1 loads in flight
    #pragma unroll
    for (int r = 0; r < 4; ++r) {
        const int k8 = 16 + r * 4 + kq;
        #pragma unroll
        for (int j = 0; j < 8; ++j) uv[r * 8 + j] = inb[(size_t)(k8 * 8 + j) * HWI + sp];
    }

    f32x4 acc[4][4] = {};
    YSTEP(A0, A1, 1, 0, acc)
    YSTEP(A1, A0, 2, 1, acc)
    YSTEP(A0, A1, 3, 2, acc)
    YSTEP(A1, A0, 4, 3, acc)

    #pragma unroll
    for (int r = 0; r < 4; ++r) {
        const int k8 = 16 + r * 4 + kq;
        short8 v8;
        #pragma unroll
        for (int j = 0; j < 8; ++j) v8[j] = (short)uv[r * 8 + j];
        *(short8*)&ys[sp][(k8 ^ (sp & 7)) * 8] = v8;
    }
    __syncthreads();

    YSTEP(A0, A1, 5, 4, acc)
    YSTEP(A1, A0, 6, 5, acc)
    YSTEP(A0, A1, 7, 6, acc)
    YSTEP(A1, A0, 0, 7, acc)   // tail prefetch harmless

    float* ob = out + (size_t)b * C_ * HWI;
    const float* rb = res + (size_t)b * C_ * HWI;
    const int pl = p0 + (lane & 15);
    #pragma unroll
    for (int i = 0; i < 4; ++i)
        #pragma unroll
        for (int r = 0; r < 4; ++r) {
            const int o = wv * 64 + i * 16 + (lane >> 4) * 4 + r;
            const float bz = bias[o];
            #pragma unroll
            for (int f = 0; f < 4; ++f) {
                const size_t off = (size_t)o * HWI + pl + f * 16;
                ob[off] = acc[i][f][r] + bz + rb[off];
            }
        }
}

// ---------------------------------------------------------------------------
// z[b,c,h,g] = sum_w f1[b,c,h,w] * f2[b,c,g,w]  (in-place safe, z == f1)
// ---------------------------------------------------------------------------
__global__ __launch_bounds__(256)
void zgemm_k(const float* f1, const float* __restrict__ f2, float* z)
{
    __shared__ float aT[64][64];
    __shared__ float bT[64][64];

    const int tid = threadIdx.x;
    const int c = blockIdx.x, b = blockIdx.y;
    const size_t base = ((size_t)b * C_ + c) * HWI;

    const int r = tid >> 2;
    const int q = (tid & 3) << 4;
    {
        const float* pa = f1 + base + (size_t)r * HDIM + q;
        const float* pb = f2 + base + (size_t)r * HDIM + q;
        float4 v0 = *(const float4*)(pa + 0);
        float4 v1 = *(const float4*)(pa + 4);
        float4 v2 = *(const float4*)(pa + 8);
        float4 v3 = *(const float4*)(pa + 12);
        float4 u0 = *(const float4*)(pb + 0);
        float4 u1 = *(const float4*)(pb + 4);
        float4 u2 = *(const float4*)(pb + 8);
        float4 u3 = *(const float4*)(pb + 12);
        float ta[16] = {v0.x,v0.y,v0.z,v0.w, v1.x,v1.y,v1.z,v1.w,
                        v2.x,v2.y,v2.z,v2.w, v3.x,v3.y,v3.z,v3.w};
        float tb[16] = {u0.x,u0.y,u0.z,u0.w, u1.x,u1.y,u1.z,u1.w,
                        u2.x,u2.y,u2.z,u2.w, u3.x,u3.y,u3.z,u3.w};
        #pragma unroll
        for (int j = 0; j < 16; ++j) { aT[q + j][r] = ta[j]; bT[q + j][r] = tb[j]; }
    }
    __syncthreads();

    const int tx = tid & 15, ty = tid >> 4;
    float acc[4][4] = {};
    #pragma unroll 8
    for (int w = 0; w < 64; ++w) {
        float4 a = *(const float4*)&aT[w][ty * 4];
        float4 g = *(const float4*)&bT[w][tx * 4];
        float av[4] = {a.x, a.y, a.z, a.w};
        float gv[4] = {g.x, g.y, g.z, g.w};
        #pragma unroll
        for (int i = 0; i < 4; ++i)
            #pragma unroll
            for (int j = 0; j < 4; ++j)
                acc[i][j] += av[i] * gv[j];
    }

    float* zb = z + base;
    #pragma unroll
    for (int i = 0; i < 4; ++i)
        *(float4*)&zb[(size_t)(ty * 4 + i) * HDIM + tx * 4] =
            make_float4(acc[i][0], acc[i][1], acc[i][2], acc[i][3]);
}

// ---------------------------------------------------------------------------
// channel-softmax denom, fixed-shift: sr = 1/sum_c e^(z-SHIFT)
// ---------------------------------------------------------------------------
__global__ __launch_bounds__(256)
void stats_k(const float* __restrict__ z, float* __restrict__ sr)
{
    const int qidx = blockIdx.x * 256 + threadIdx.x;
    const int b = qidx >> 12, p = qidx & 4095;
    const float* zp = z + (size_t)b * C_ * HWI + p;
    float s = 0.f;
    for (int c0 = 0; c0 < C_; c0 += 8) {
        float v[8];
        #pragma unroll
        for (int j = 0; j < 8; ++j) v[j] = zp[(size_t)(c0 + j) * HWI];
        float e = 0.f;
        #pragma unroll
        for (int j = 0; j < 8; ++j) e += __expf(v[j] - SHIFT);
        s += e;
    }
    sr[qidx] = 1.0f / s;
}

// ---------------------------------------------------------------------------
// out1[b,c,h,w] = sum_g P[c,h,g] * g1[b,c,g,w];  P = e^(z-SHIFT)*sr[b,h*64+g]
// g1 bf16 in, out1 bf16 out.
// ---------------------------------------------------------------------------
__global__ __launch_bounds__(256)
void pvgemm_k(const float* __restrict__ z, const float* __restrict__ sr,
              const unsigned short* __restrict__ g1,
              unsigned short* __restrict__ out1)
{
    __shared__ float pT[64][64];  // [g][h]
    __shared__ float gl[64][64];  // [g][w]

    const int tid = threadIdx.x;
    const int c = blockIdx.x, b = blockIdx.y;
    const size_t base = ((size_t)b * C_ + c) * HWI;

    const int r = tid >> 2;
    const int q = (tid & 3) << 4;
    {
        const float* zp = z  + base + (size_t)r * HDIM + q;
        const float* rp = sr + (size_t)b * HWI + (size_t)r * HDIM + q;
        const unsigned short* gp = g1 + base + (size_t)r * HDIM + q;
        float pv[16], gv[16];
        #pragma unroll
        for (int j = 0; j < 4; ++j) {
            float4 zv = *(const float4*)(zp + j * 4);
            float4 rv = *(const float4*)(rp + j * 4);
            pv[j*4+0] = __expf(zv.x - SHIFT) * rv.x;
            pv[j*4+1] = __expf(zv.y - SHIFT) * rv.y;
            pv[j*4+2] = __expf(zv.z - SHIFT) * rv.z;
            pv[j*4+3] = __expf(zv.w - SHIFT) * rv.w;
        }
        short8 ga = *(const short8*)(gp + 0);
        short8 gb = *(const short8*)(gp + 8);
        #pragma unroll
        for (int j = 0; j < 8; ++j) { gv[j] = bf2f((unsigned short)ga[j]); gv[8 + j] = bf2f((unsigned short)gb[j]); }
        #pragma unroll
        for (int j = 0; j < 16; ++j) { pT[q + j][r] = pv[j]; gl[r][q + j] = gv[j]; }
    }
    __syncthreads();

    const int tx = tid & 15, ty = tid >> 4;
    float acc[4][4] = {};
    #pragma unroll 8
    for (int g = 0; g < 64; ++g) {
        float4 a = *(const float4*)&pT[g][ty * 4];
        float4 vv4 = *(const float4*)&gl[g][tx * 4];
        float av[4] = {a.x, a.y, a.z, a.w};
        float vv[4] = {vv4.x, vv4.y, vv4.z, vv4.w};
        #pragma unroll
        for (int i = 0; i < 4; ++i)
            #pragma unroll
            for (int j = 0; j < 4; ++j)
                acc[i][j] += av[i] * vv[j];
    }

    unsigned short* ob = out1 + base;
    #pragma unroll
    for (int i = 0; i < 4; ++i) {
        s4v w;
        #pragma unroll
        for (int j = 0; j < 4; ++j) w[j] = (short)f2bf(acc[i][j]);
        *(s4v*)&ob[(size_t)(ty * 4 + i) * HDIM + tx * 4] = w;
    }
}

// ---------------------------------------------------------------------------
extern "C" void kernel_launch(void* const* d_in, const int* in_sizes, int n_in,
                              void* d_out, int out_size, void* d_ws, size_t ws_size,
                              hipStream_t stream)
{
    (void)in_sizes; (void)n_in; (void)out_size;
    const float* x  = (const float*)d_in[0];
    const float* wq = (const float*)d_in[1];
    const float* bq = (const float*)d_in[2];
    const float* wv = (const float*)d_in[3];
    const float* bv = (const float*)d_in[4];
    const float* wk = (const float*)d_in[5];
    const float* bk = (const float*)d_in[6];
    const float* wy = (const float*)d_in[7];
    const float* by = (const float*)d_in[8];
    float* out = (float*)d_out;

    const size_t N  = (size_t)B_ * C_ * HWI;   // 33,554,432
    const size_t NS = (size_t)B_ * HWI;        // 131,072

    char* wsb = (char*)d_ws;
    short* wsp = (short*)wsb;
    const size_t wbytes = 8 * (size_t)NW * sizeof(short);   // 1 MB
    char* fb = wsb + wbytes;

    dim3 blk(256);
    hipLaunchKernelGGL(wsplit_k, dim3(32), blk, 0, stream, wq, wsp + 0 * NW, wsp + 1 * NW);
    hipLaunchKernelGGL(wsplit_k, dim3(32), blk, 0, stream, wv, wsp + 2 * NW, wsp + 3 * NW);
    hipLaunchKernelGGL(wsplit_k, dim3(32), blk, 0, stream, wk, wsp + 4 * NW, wsp + 5 * NW);
    hipLaunchKernelGGL(wsplit_k, dim3(32), blk, 0, stream, wy, wsp + 6 * NW, wsp + 7 * NW);
    const short* wqvk = wsp;
    const short* why  = wsp + 6 * NW;
    const short* wly  = wsp + 7 * NW;

    dim3 cgrid(HWI / 64, B_);     // 2048 blocks
    dim3 zgrid(C_, B_);
    dim3 sgrid((unsigned)(NS / 256));

    // bigws layout: f2[N f32] | g1b[N bf16] | out1b[N bf16] | sr[NS f32]
    const bool bigws = ws_size >= wbytes + 4 * N + 2 * N + 2 * N + 4 * NS;

    if (bigws) {
        float*          f2   = (float*)fb;
        unsigned short* g1b  = (unsigned short*)(fb + 4 * N);
        unsigned short* o1b  = (unsigned short*)(fb + 6 * N);
        float*          sr   = (float*)(fb + 8 * N);
        hipLaunchKernelGGL((convN_k<3, true>), cgrid, blk, 0, stream,
                           x, wqvk, bq, bv, bk, out, f2, g1b);
        hipLaunchKernelGGL(zgemm_k,  zgrid, blk, 0, stream, out, f2, out);   // z in place
        hipLaunchKernelGGL(stats_k,  sgrid, blk, 0, stream, out, sr);
        hipLaunchKernelGGL(pvgemm_k, zgrid, blk, 0, stream, out, sr, g1b, o1b);
        hipLaunchKernelGGL(convY_k,  cgrid, blk, 0, stream, o1b, x, why, wly, by, out);
    } else {
        float*          f2  = (float*)fb;
        unsigned short* g1b = (unsigned short*)fb;
        unsigned short* o1b = (unsigned short*)fb + N;
        float*          sr  = (float*)(fb + 4 * N);
        hipLaunchKernelGGL((convN_k<2, false>), cgrid, blk, 0, stream,
                           x, wqvk, bq, bv, (const float*)0, out, f2, (void*)0);
        hipLaunchKernelGGL(zgemm_k,  zgrid, blk, 0, stream, out, f2, out);   // z in place
        hipLaunchKernelGGL(stats_k,  sgrid, blk, 0, stream, out, sr);
        hipLaunchKernelGGL((convN_k<1, true>), cgrid, blk, 0, stream,
                           x, wqvk + 4 * (size_t)NW, bk, (const float*)0, (const float*)0,
                           g1b, (void*)0, (void*)0);
        hipLaunchKernelGGL(pvgemm_k, zgrid, blk, 0, stream, out, sr, g1b, o1b);
        hipLaunchKernelGGL(convY_k,  cgrid, blk, 0, stream, o1b, x, why, wly, by, out);
    }
}

// Round 7
// 428.335 us; speedup vs baseline: 1.3028x; 1.3028x over previous
//
#include <hip/hip_runtime.h>
#include <hip/hip_bf16.h>

#define B_    32
#define C_    256
#define HWI   4096   // 64*64
#define HDIM  64
#define NW    65536  // elems per weight matrix (256x256)
#define SHIFT 20.0f  // fixed softmax shift

typedef short short8 __attribute__((ext_vector_type(8)));
typedef short s4v    __attribute__((ext_vector_type(4)));
typedef float f32x4  __attribute__((ext_vector_type(4)));

__device__ __forceinline__ unsigned short f2bf(float x) {
    __hip_bfloat16 t = __float2bfloat16(x);          // RNE hw cvt
    return *reinterpret_cast<unsigned short*>(&t);
}
__device__ __forceinline__ float bf2f(unsigned short b) {
    return __uint_as_float((unsigned)b << 16);
}
// split fp32 -> bf16 hi + bf16 lo. Pair is self-correcting: lo rounds the
// exact remainder x - hi, so pair sum error ~2^-16 relative regardless of
// hi's rounding mode.
__device__ __forceinline__ void f2bf_pair(float x, short& h, short& l) {
    unsigned short hb = f2bf(x);
    h = (short)hb;
    l = (short)f2bf(x - bf2f(hb));
}

// ---------------------------------------------------------------------------
// Pre-split ALL 4 weight matrices fp32 -> bf16 hi/lo, MFMA-fragment-linear:
// flat = (o>>4)*4096 + (k>>3)*128 + (o&15)*8 + (k&7). grid (32, 4)
// ---------------------------------------------------------------------------
__global__ __launch_bounds__(256)
void wsplit4_k(const float* __restrict__ w0, const float* __restrict__ w1,
               const float* __restrict__ w2, const float* __restrict__ w3,
               short* __restrict__ dst)
{
    const int m = blockIdx.y;
    const float* w = (m == 0) ? w0 : (m == 1) ? w1 : (m == 2) ? w2 : w3;
    short* wh = dst + (size_t)m * 2 * NW;
    short* wl = wh + NW;

    const int g  = blockIdx.x * 256 + threadIdx.x;
    const int o  = g >> 5, k8 = g & 31;
    const float* src = w + o * 256 + k8 * 8;
    const int d = (o >> 4) * 4096 + k8 * 128 + (o & 15) * 8;
    short8 h8, l8;
    #pragma unroll
    for (int j = 0; j < 8; ++j) { short h, l; f2bf_pair(src[j], h, l); h8[j] = h; l8[j] = l; }
    *(short8*)(wh + d) = h8;
    *(short8*)(wl + d) = l8;
}

// ---------------------------------------------------------------------------
// building blocks (round-5 structure)
// ---------------------------------------------------------------------------
__device__ __forceinline__ void stage_load(const float* __restrict__ inb,
                                           int half, int sp, int kq, float* v)
{
    #pragma unroll
    for (int r = 0; r < 4; ++r) {
        const int k8 = half * 16 + r * 4 + kq;
        const float* gx = inb + (size_t)(k8 * 8) * HWI + sp;
        #pragma unroll
        for (int j = 0; j < 8; ++j) v[r * 8 + j] = gx[(size_t)j * HWI];
    }
}

__device__ __forceinline__ void stage_write(int half, int sp, int kq,
        const float* v, short (*xh)[256], short (*xl)[256])
{
    #pragma unroll
    for (int r = 0; r < 4; ++r) {
        const int k8 = half * 16 + r * 4 + kq;
        short8 h8, l8;
        #pragma unroll
        for (int j = 0; j < 8; ++j) {
            short h, l; f2bf_pair(v[r * 8 + j], h, l); h8[j] = h; l8[j] = l;
        }
        const int ch = (k8 ^ (sp & 7)) * 8;
        *(short8*)&xh[sp][ch] = h8;
        *(short8*)&xl[sp][ch] = l8;
    }
}

__device__ __forceinline__ void conv_step(int s, int lane, int o16b,
        const short* __restrict__ wh, const short* __restrict__ wl,
        const short (*xh)[256], const short (*xl)[256], f32x4 acc[4][4])
{
    const int k8 = s * 4 + (lane >> 4);
    short8 ah[4], al[4], bh[4], bl[4];
    #pragma unroll
    for (int i = 0; i < 4; ++i) {
        const int aoff = ((o16b + i) * 32 + k8) * 128 + (lane & 15) * 8;
        ah[i] = *(const short8*)(wh + aoff);
        al[i] = *(const short8*)(wl + aoff);
    }
    #pragma unroll
    for (int f = 0; f < 4; ++f) {
        const int pr = f * 16 + (lane & 15);
        const int ch = (k8 ^ (pr & 7)) * 8;
        bh[f] = *(const short8*)&xh[pr][ch];
        bl[f] = *(const short8*)&xl[pr][ch];
    }
    __builtin_amdgcn_s_setprio(1);
    #pragma unroll
    for (int i = 0; i < 4; ++i)
        #pragma unroll
        for (int f = 0; f < 4; ++f) {
            acc[i][f] = __builtin_amdgcn_mfma_f32_16x16x32_bf16(ah[i], bh[f], acc[i][f], 0, 0, 0);
            acc[i][f] = __builtin_amdgcn_mfma_f32_16x16x32_bf16(al[i], bh[f], acc[i][f], 0, 0, 0);
            acc[i][f] = __builtin_amdgcn_mfma_f32_16x16x32_bf16(ah[i], bl[f], acc[i][f], 0, 0, 0);
        }
    __builtin_amdgcn_s_setprio(0);
}

__device__ __forceinline__ void conv_epi_f32(const f32x4 acc[4][4],
        const float* __restrict__ bias, float* __restrict__ ob,
        int p0, int wv, int lane)
{
    const int pl = p0 + (lane & 15);
    #pragma unroll
    for (int i = 0; i < 4; ++i)
        #pragma unroll
        for (int r = 0; r < 4; ++r) {
            const int o = wv * 64 + i * 16 + (lane >> 4) * 4 + r;
            const float bz = bias[o];
            #pragma unroll
            for (int f = 0; f < 4; ++f)
                ob[(size_t)o * HWI + pl + f * 16] = acc[i][f][r] + bz;
        }
}

__device__ __forceinline__ void conv_epi_bf16(const f32x4 acc[4][4],
        const float* __restrict__ bias, unsigned short* __restrict__ ob,
        int p0, int wv, int lane)
{
    const int pl = p0 + (lane & 15);
    #pragma unroll
    for (int i = 0; i < 4; ++i)
        #pragma unroll
        for (int r = 0; r < 4; ++r) {
            const int o = wv * 64 + i * 16 + (lane >> 4) * 4 + r;
            const float bz = bias[o];
            #pragma unroll
            for (int f = 0; f < 4; ++f)
                ob[(size_t)o * HWI + pl + f * 16] = f2bf(acc[i][f][r] + bz);
        }
}

// ---------------------------------------------------------------------------
// Fused 1x1 convs (fp32 in, bf16x3 MFMA). Block = 256 thr (4 waves), p-tile
// 64, K=256 staged in LDS as bf16 h/l in two halves (split-stage pipeline).
// XCD-chunked swizzle. Last output bf16 when G1B. grid: (HWI/64, B_)
// ---------------------------------------------------------------------------
template<int NOUT, bool G1B>
__global__ __launch_bounds__(256)
void convN_k(const float* __restrict__ in, const short* __restrict__ wb,
             const float* __restrict__ b0, const float* __restrict__ b1,
             const float* __restrict__ b2,
             void* o0, void* o1, void* o2)
{
    __shared__ short xh[64][256];
    __shared__ short xl[64][256];

    const int tid  = threadIdx.x;
    const int lane = tid & 63;
    const int wv   = tid >> 6;

    const int id    = blockIdx.y * gridDim.x + blockIdx.x;
    const int chunk = (gridDim.x * gridDim.y) >> 3;
    const int nid   = (id & 7) * chunk + (id >> 3);
    const int p0    = (nid & 63) * 64;
    const int b     = nid >> 6;

    const float* inb = in + (size_t)b * C_ * HWI + p0;
    const int sp = tid & 63, kq = tid >> 6;

    float v[32];
    stage_load(inb, 0, sp, kq, v);
    stage_write(0, sp, kq, v, xh, xl);
    __syncthreads();

    const int o16b = wv * 4;
    const size_t obase = (size_t)b * C_ * HWI;

    // conv0 with split-stage overlap
    stage_load(inb, 1, sp, kq, v);
    f32x4 acc[4][4] = {};
    #pragma unroll
    for (int s = 0; s < 4; ++s)
        conv_step(s, lane, o16b, wb, wb + NW, xh, xl, acc);
    stage_write(1, sp, kq, v, xh, xl);
    __syncthreads();
    #pragma unroll
    for (int s = 4; s < 8; ++s)
        conv_step(s, lane, o16b, wb, wb + NW, xh, xl, acc);

    if (G1B && NOUT == 1)
        conv_epi_bf16(acc, b0, (unsigned short*)o0 + obase, p0, wv, lane);
    else
        conv_epi_f32(acc, b0, (float*)o0 + obase, p0, wv, lane);

    #pragma unroll
    for (int cv = 1; cv < NOUT; ++cv) {
        const short* wh   = wb + (size_t)cv * 2 * NW;
        const float* bias = (cv == 1) ? b1 : b2;
        void*        op   = (cv == 1) ? o1 : o2;
        f32x4 acc2[4][4] = {};
        #pragma unroll 2
        for (int s = 0; s < 8; ++s)
            conv_step(s, lane, o16b, wh, wh + NW, xh, xl, acc2);
        if (G1B && cv == NOUT - 1)
            conv_epi_bf16(acc2, bias, (unsigned short*)op + obase, p0, wv, lane);
        else
            conv_epi_f32(acc2, bias, (float*)op + obase, p0, wv, lane);
    }
}

// ---------------------------------------------------------------------------
// Final conv: bf16 input, 2-term MFMA, +bias +residual -> fp32. 32 KB LDS.
// ---------------------------------------------------------------------------
__global__ __launch_bounds__(256, 3)
void convY_k(const unsigned short* __restrict__ in, const float* __restrict__ res,
             const short* __restrict__ wh, const short* __restrict__ wl,
             const float* __restrict__ bias, float* __restrict__ out)
{
    __shared__ short ys[64][256];   // 32 KB

    const int tid  = threadIdx.x;
    const int lane = tid & 63;
    const int wv   = tid >> 6;

    const int id    = blockIdx.y * gridDim.x + blockIdx.x;
    const int chunk = (gridDim.x * gridDim.y) >> 3;
    const int nid   = (id & 7) * chunk + (id >> 3);
    const int p0    = (nid & 63) * 64;
    const int b     = nid >> 6;

    const unsigned short* inb = in + (size_t)b * C_ * HWI + p0;
    const int sp = tid & 63, kq = tid >> 6;

    unsigned short uv[32];

    // stage half 0
    #pragma unroll
    for (int r = 0; r < 4; ++r) {
        const int k8 = r * 4 + kq;
        #pragma unroll
        for (int j = 0; j < 8; ++j) uv[r * 8 + j] = inb[(size_t)(k8 * 8 + j) * HWI + sp];
    }
    #pragma unroll
    for (int r = 0; r < 4; ++r) {
        const int k8 = r * 4 + kq;
        short8 v8;
        #pragma unroll
        for (int j = 0; j < 8; ++j) v8[j] = (short)uv[r * 8 + j];
        *(short8*)&ys[sp][(k8 ^ (sp & 7)) * 8] = v8;
    }
    __syncthreads();

    // issue half-1 loads
    #pragma unroll
    for (int r = 0; r < 4; ++r) {
        const int k8 = 16 + r * 4 + kq;
        #pragma unroll
        for (int j = 0; j < 8; ++j) uv[r * 8 + j] = inb[(size_t)(k8 * 8 + j) * HWI + sp];
    }

    const int o16b = wv * 4;
    f32x4 acc[4][4] = {};

    #pragma unroll
    for (int s = 0; s < 4; ++s) {
        const int k8 = s * 4 + (lane >> 4);
        short8 ah[4], al[4], bh[4];
        #pragma unroll
        for (int i = 0; i < 4; ++i) {
            const int aoff = ((o16b + i) * 32 + k8) * 128 + (lane & 15) * 8;
            ah[i] = *(const short8*)(wh + aoff);
            al[i] = *(const short8*)(wl + aoff);
        }
        #pragma unroll
        for (int f = 0; f < 4; ++f) {
            const int pr = f * 16 + (lane & 15);
            bh[f] = *(const short8*)&ys[pr][(k8 ^ (pr & 7)) * 8];
        }
        __builtin_amdgcn_s_setprio(1);
        #pragma unroll
        for (int i = 0; i < 4; ++i)
            #pragma unroll
            for (int f = 0; f < 4; ++f) {
                acc[i][f] = __builtin_amdgcn_mfma_f32_16x16x32_bf16(ah[i], bh[f], acc[i][f], 0, 0, 0);
                acc[i][f] = __builtin_amdgcn_mfma_f32_16x16x32_bf16(al[i], bh[f], acc[i][f], 0, 0, 0);
            }
        __builtin_amdgcn_s_setprio(0);
    }

    #pragma unroll
    for (int r = 0; r < 4; ++r) {
        const int k8 = 16 + r * 4 + kq;
        short8 v8;
        #pragma unroll
        for (int j = 0; j < 8; ++j) v8[j] = (short)uv[r * 8 + j];
        *(short8*)&ys[sp][(k8 ^ (sp & 7)) * 8] = v8;
    }
    __syncthreads();

    #pragma unroll
    for (int s = 4; s < 8; ++s) {
        const int k8 = s * 4 + (lane >> 4);
        short8 ah[4], al[4], bh[4];
        #pragma unroll
        for (int i = 0; i < 4; ++i) {
            const int aoff = ((o16b + i) * 32 + k8) * 128 + (lane & 15) * 8;
            ah[i] = *(const short8*)(wh + aoff);
            al[i] = *(const short8*)(wl + aoff);
        }
        #pragma unroll
        for (int f = 0; f < 4; ++f) {
            const int pr = f * 16 + (lane & 15);
            bh[f] = *(const short8*)&ys[pr][(k8 ^ (pr & 7)) * 8];
        }
        __builtin_amdgcn_s_setprio(1);
        #pragma unroll
        for (int i = 0; i < 4; ++i)
            #pragma unroll
            for (int f = 0; f < 4; ++f) {
                acc[i][f] = __builtin_amdgcn_mfma_f32_16x16x32_bf16(ah[i], bh[f], acc[i][f], 0, 0, 0);
                acc[i][f] = __builtin_amdgcn_mfma_f32_16x16x32_bf16(al[i], bh[f], acc[i][f], 0, 0, 0);
            }
        __builtin_amdgcn_s_setprio(0);
    }

    float* ob = out + (size_t)b * C_ * HWI;
    const float* rb = res + (size_t)b * C_ * HWI;
    const int pl = p0 + (lane & 15);
    #pragma unroll
    for (int i = 0; i < 4; ++i)
        #pragma unroll
        for (int r = 0; r < 4; ++r) {
            const int o = wv * 64 + i * 16 + (lane >> 4) * 4 + r;
            const float bz = bias[o];
            #pragma unroll
            for (int f = 0; f < 4; ++f) {
                const size_t off = (size_t)o * HWI + pl + f * 16;
                ob[off] = acc[i][f][r] + bz + rb[off];
            }
        }
}

// ---------------------------------------------------------------------------
// z[b,c,h,g] = sum_w f1[b,c,h,w] * f2[b,c,g,w]  (in-place safe, z == f1)
// ---------------------------------------------------------------------------
__global__ __launch_bounds__(256)
void zgemm_k(const float* f1, const float* __restrict__ f2, float* z)
{
    __shared__ float aT[64][64];
    __shared__ float bT[64][64];

    const int tid = threadIdx.x;
    const int c = blockIdx.x, b = blockIdx.y;
    const size_t base = ((size_t)b * C_ + c) * HWI;

    const int r = tid >> 2;
    const int q = (tid & 3) << 4;
    {
        const float* pa = f1 + base + (size_t)r * HDIM + q;
        const float* pb = f2 + base + (size_t)r * HDIM + q;
        float4 v0 = *(const float4*)(pa + 0);
        float4 v1 = *(const float4*)(pa + 4);
        float4 v2 = *(const float4*)(pa + 8);
        float4 v3 = *(const float4*)(pa + 12);
        float4 u0 = *(const float4*)(pb + 0);
        float4 u1 = *(const float4*)(pb + 4);
        float4 u2 = *(const float4*)(pb + 8);
        float4 u3 = *(const float4*)(pb + 12);
        float ta[16] = {v0.x,v0.y,v0.z,v0.w, v1.x,v1.y,v1.z,v1.w,
                        v2.x,v2.y,v2.z,v2.w, v3.x,v3.y,v3.z,v3.w};
        float tb[16] = {u0.x,u0.y,u0.z,u0.w, u1.x,u1.y,u1.z,u1.w,
                        u2.x,u2.y,u2.z,u2.w, u3.x,u3.y,u3.z,u3.w};
        #pragma unroll
        for (int j = 0; j < 16; ++j) { aT[q + j][r] = ta[j]; bT[q + j][r] = tb[j]; }
    }
    __syncthreads();

    const int tx = tid & 15, ty = tid >> 4;
    float acc[4][4] = {};
    #pragma unroll 8
    for (int w = 0; w < 64; ++w) {
        float4 a = *(const float4*)&aT[w][ty * 4];
        float4 g = *(const float4*)&bT[w][tx * 4];
        float av[4] = {a.x, a.y, a.z, a.w};
        float gv[4] = {g.x, g.y, g.z, g.w};
        #pragma unroll
        for (int i = 0; i < 4; ++i)
            #pragma unroll
            for (int j = 0; j < 4; ++j)
                acc[i][j] += av[i] * gv[j];
    }

    float* zb = z + base;
    #pragma unroll
    for (int i = 0; i < 4; ++i)
        *(float4*)&zb[(size_t)(ty * 4 + i) * HDIM + tx * 4] =
            make_float4(acc[i][0], acc[i][1], acc[i][2], acc[i][3]);
}

// ---------------------------------------------------------------------------
// channel-softmax denom, fixed-shift: sr = 1/sum_c e^(z-SHIFT)
// ---------------------------------------------------------------------------
__global__ __launch_bounds__(256)
void stats_k(const float* __restrict__ z, float* __restrict__ sr)
{
    const int qidx = blockIdx.x * 256 + threadIdx.x;
    const int b = qidx >> 12, p = qidx & 4095;
    const float* zp = z + (size_t)b * C_ * HWI + p;
    float s = 0.f;
    for (int c0 = 0; c0 < C_; c0 += 8) {
        float v[8];
        #pragma unroll
        for (int j = 0; j < 8; ++j) v[j] = zp[(size_t)(c0 + j) * HWI];
        float e = 0.f;
        #pragma unroll
        for (int j = 0; j < 8; ++j) e += __expf(v[j] - SHIFT);
        s += e;
    }
    sr[qidx] = 1.0f / s;
}

// ---------------------------------------------------------------------------
// out1[b,c,h,w] = sum_g P[c,h,g] * g1[b,c,g,w];  P = e^(z-SHIFT)*sr[b,h*64+g]
// g1 bf16 in, out1 bf16 out.
// ---------------------------------------------------------------------------
__global__ __launch_bounds__(256)
void pvgemm_k(const float* __restrict__ z, const float* __restrict__ sr,
              const unsigned short* __restrict__ g1,
              unsigned short* __restrict__ out1)
{
    __shared__ float pT[64][64];  // [g][h]
    __shared__ float gl[64][64];  // [g][w]

    const int tid = threadIdx.x;
    const int c = blockIdx.x, b = blockIdx.y;
    const size_t base = ((size_t)b * C_ + c) * HWI;

    const int r = tid >> 2;
    const int q = (tid & 3) << 4;
    {
        const float* zp = z  + base + (size_t)r * HDIM + q;
        const float* rp = sr + (size_t)b * HWI + (size_t)r * HDIM + q;
        const unsigned short* gp = g1 + base + (size_t)r * HDIM + q;
        float pv[16], gv[16];
        #pragma unroll
        for (int j = 0; j < 4; ++j) {
            float4 zv = *(const float4*)(zp + j * 4);
            float4 rv = *(const float4*)(rp + j * 4);
            pv[j*4+0] = __expf(zv.x - SHIFT) * rv.x;
            pv[j*4+1] = __expf(zv.y - SHIFT) * rv.y;
            pv[j*4+2] = __expf(zv.z - SHIFT) * rv.z;
            pv[j*4+3] = __expf(zv.w - SHIFT) * rv.w;
        }
        short8 ga = *(const short8*)(gp + 0);
        short8 gb = *(const short8*)(gp + 8);
        #pragma unroll
        for (int j = 0; j < 8; ++j) { gv[j] = bf2f((unsigned short)ga[j]); gv[8 + j] = bf2f((unsigned short)gb[j]); }
        #pragma unroll
        for (int j = 0; j < 16; ++j) { pT[q + j][r] = pv[j]; gl[r][q + j] = gv[j]; }
    }
    __syncthreads();

    const int tx = tid & 15, ty = tid >> 4;
    float acc[4][4] = {};
    #pragma unroll 8
    for (int g = 0; g < 64; ++g) {
        float4 a = *(const float4*)&pT[g][ty * 4];
        float4 vv4 = *(const float4*)&gl[g][tx * 4];
        float av[4] = {a.x, a.y, a.z, a.w};
        float vv[4] = {vv4.x, vv4.y, vv4.z, vv4.w};
        #pragma unroll
        for (int i = 0; i < 4; ++i)
            #pragma unroll
            for (int j = 0; j < 4; ++j)
                acc[i][j] += av[i] * vv[j];
    }

    unsigned short* ob = out1 + base;
    #pragma unroll
    for (int i = 0; i < 4; ++i) {
        s4v w;
        #pragma unroll
        for (int j = 0; j < 4; ++j) w[j] = (short)f2bf(acc[i][j]);
        *(s4v*)&ob[(size_t)(ty * 4 + i) * HDIM + tx * 4] = w;
    }
}

// ---------------------------------------------------------------------------
extern "C" void kernel_launch(void* const* d_in, const int* in_sizes, int n_in,
                              void* d_out, int out_size, void* d_ws, size_t ws_size,
                              hipStream_t stream)
{
    (void)in_sizes; (void)n_in; (void)out_size;
    const float* x  = (const float*)d_in[0];
    const float* wq = (const float*)d_in[1];
    const float* bq = (const float*)d_in[2];
    const float* wv = (const float*)d_in[3];
    const float* bv = (const float*)d_in[4];
    const float* wk = (const float*)d_in[5];
    const float* bk = (const float*)d_in[6];
    const float* wy = (const float*)d_in[7];
    const float* by = (const float*)d_in[8];
    float* out = (float*)d_out;

    const size_t N  = (size_t)B_ * C_ * HWI;   // 33,554,432
    const size_t NS = (size_t)B_ * HWI;        // 131,072

    char* wsb = (char*)d_ws;
    short* wsp = (short*)wsb;
    const size_t wbytes = 8 * (size_t)NW * sizeof(short);   // 1 MB
    char* fb = wsb + wbytes;

    dim3 blk(256);
    hipLaunchKernelGGL(wsplit4_k, dim3(32, 4), blk, 0, stream, wq, wv, wk, wy, wsp);
    const short* wqvk = wsp;
    const short* why  = wsp + 6 * NW;
    const short* wly  = wsp + 7 * NW;

    dim3 cgrid(HWI / 64, B_);     // 2048 blocks
    dim3 zgrid(C_, B_);
    dim3 sgrid((unsigned)(NS / 256));

    // bigws layout: f2[N f32] | g1b[N bf16] | out1b[N bf16] | sr[NS f32]
    const bool bigws = ws_size >= wbytes + 4 * N + 2 * N + 2 * N + 4 * NS;

    if (bigws) {
        float*          f2   = (float*)fb;
        unsigned short* g1b  = (unsigned short*)(fb + 4 * N);
        unsigned short* o1b  = (unsigned short*)(fb + 6 * N);
        float*          sr   = (float*)(fb + 8 * N);
        hipLaunchKernelGGL((convN_k<3, true>), cgrid, blk, 0, stream,
                           x, wqvk, bq, bv, bk, out, f2, g1b);
        hipLaunchKernelGGL(zgemm_k,  zgrid, blk, 0, stream, out, f2, out);   // z in place
        hipLaunchKernelGGL(stats_k,  sgrid, blk, 0, stream, out, sr);
        hipLaunchKernelGGL(pvgemm_k, zgrid, blk, 0, stream, out, sr, g1b, o1b);
        hipLaunchKernelGGL(convY_k,  cgrid, blk, 0, stream, o1b, x, why, wly, by, out);
    } else {
        float*          f2  = (float*)fb;
        unsigned short* g1b = (unsigned short*)fb;
        unsigned short* o1b = (unsigned short*)fb + N;
        float*          sr  = (float*)(fb + 4 * N);
        hipLaunchKernelGGL((convN_k<2, false>), cgrid, blk, 0, stream,
                           x, wqvk, bq, bv, (const float*)0, out, f2, (void*)0);
        hipLaunchKernelGGL(zgemm_k,  zgrid, blk, 0, stream, out, f2, out);   // z in place
        hipLaunchKernelGGL(stats_k,  sgrid, blk, 0, stream, out, sr);
        hipLaunchKernelGGL((convN_k<1, true>), cgrid, blk, 0, stream,
                           x, wqvk + 4 * (size_t)NW, bk, (const float*)0, (const float*)0,
                           g1b, (void*)0, (void*)0);
        hipLaunchKernelGGL(pvgemm_k, zgrid, blk, 0, stream, out, sr, g1b, o1b);
        hipLaunchKernelGGL(convY_k,  cgrid, blk, 0, stream, o1b, x, why, wly, by, out);
    }
}

// Round 9
// 380.181 us; speedup vs baseline: 1.4679x; 1.1267x over previous
//
#include <hip/hip_runtime.h>
#include <hip/hip_bf16.h>

#define B_    32
#define C_    256
#define HWI   4096   // 64*64
#define HDIM  64
#define NW    65536  // elems per weight matrix (256x256)
#define SHIFT 20.0f  // fixed softmax shift

typedef short short8 __attribute__((ext_vector_type(8)));
typedef short s4v    __attribute__((ext_vector_type(4)));
typedef float f32x4  __attribute__((ext_vector_type(4)));

#define MFMA(a, b, c) __builtin_amdgcn_mfma_f32_16x16x32_bf16(a, b, c, 0, 0, 0)

__device__ __forceinline__ unsigned short f2bf(float x) {
    __hip_bfloat16 t = __float2bfloat16(x);          // RNE hw cvt
    return *reinterpret_cast<unsigned short*>(&t);
}
__device__ __forceinline__ float bf2f(unsigned short b) {
    return __uint_as_float((unsigned)b << 16);
}
// split fp32 -> bf16 hi + bf16 lo (lo rounds exact remainder; self-correcting)
__device__ __forceinline__ void f2bf_pair(float x, short& h, short& l) {
    unsigned short hb = f2bf(x);
    h = (short)hb;
    l = (short)f2bf(x - bf2f(hb));
}

// ---------------------------------------------------------------------------
// Pre-split ALL 4 weight matrices fp32 -> bf16 hi/lo, MFMA-fragment-linear:
// flat = (o>>4)*4096 + (k>>3)*128 + (o&15)*8 + (k&7). grid (32, 4)
// ---------------------------------------------------------------------------
__global__ __launch_bounds__(256)
void wsplit4_k(const float* __restrict__ w0, const float* __restrict__ w1,
               const float* __restrict__ w2, const float* __restrict__ w3,
               short* __restrict__ dst)
{
    const int m = blockIdx.y;
    const float* w = (m == 0) ? w0 : (m == 1) ? w1 : (m == 2) ? w2 : w3;
    short* wh = dst + (size_t)m * 2 * NW;
    short* wl = wh + NW;

    const int g  = blockIdx.x * 256 + threadIdx.x;
    const int o  = g >> 5, k8 = g & 31;
    const float* src = w + o * 256 + k8 * 8;
    const int d = (o >> 4) * 4096 + k8 * 128 + (o & 15) * 8;
    short8 h8, l8;
    #pragma unroll
    for (int j = 0; j < 8; ++j) { short h, l; f2bf_pair(src[j], h, l); h8[j] = h; l8[j] = l; }
    *(short8*)(wh + d) = h8;
    *(short8*)(wl + d) = l8;
}

// ---------------------------------------------------------------------------
// conv building blocks (round-7 proven structure)
// ---------------------------------------------------------------------------
__device__ __forceinline__ void stage_load(const float* __restrict__ inb,
                                           int half, int sp, int kq, float* v)
{
    #pragma unroll
    for (int r = 0; r < 4; ++r) {
        const int k8 = half * 16 + r * 4 + kq;
        const float* gx = inb + (size_t)(k8 * 8) * HWI + sp;
        #pragma unroll
        for (int j = 0; j < 8; ++j) v[r * 8 + j] = gx[(size_t)j * HWI];
    }
}

__device__ __forceinline__ void stage_write(int half, int sp, int kq,
        const float* v, short (*xh)[256], short (*xl)[256])
{
    #pragma unroll
    for (int r = 0; r < 4; ++r) {
        const int k8 = half * 16 + r * 4 + kq;
        short8 h8, l8;
        #pragma unroll
        for (int j = 0; j < 8; ++j) {
            short h, l; f2bf_pair(v[r * 8 + j], h, l); h8[j] = h; l8[j] = l;
        }
        const int ch = (k8 ^ (sp & 7)) * 8;
        *(short8*)&xh[sp][ch] = h8;
        *(short8*)&xl[sp][ch] = l8;
    }
}

__device__ __forceinline__ void conv_step(int s, int lane, int o16b,
        const short* __restrict__ wh, const short* __restrict__ wl,
        const short (*xh)[256], const short (*xl)[256], f32x4 acc[4][4])
{
    const int k8 = s * 4 + (lane >> 4);
    short8 ah[4], al[4], bh[4], bl[4];
    #pragma unroll
    for (int i = 0; i < 4; ++i) {
        const int aoff = ((o16b + i) * 32 + k8) * 128 + (lane & 15) * 8;
        ah[i] = *(const short8*)(wh + aoff);
        al[i] = *(const short8*)(wl + aoff);
    }
    #pragma unroll
    for (int f = 0; f < 4; ++f) {
        const int pr = f * 16 + (lane & 15);
        const int ch = (k8 ^ (pr & 7)) * 8;
        bh[f] = *(const short8*)&xh[pr][ch];
        bl[f] = *(const short8*)&xl[pr][ch];
    }
    __builtin_amdgcn_s_setprio(1);
    #pragma unroll
    for (int i = 0; i < 4; ++i)
        #pragma unroll
        for (int f = 0; f < 4; ++f) {
            acc[i][f] = MFMA(ah[i], bh[f], acc[i][f]);
            acc[i][f] = MFMA(al[i], bh[f], acc[i][f]);
            acc[i][f] = MFMA(ah[i], bl[f], acc[i][f]);
        }
    __builtin_amdgcn_s_setprio(0);
}

__device__ __forceinline__ void conv_epi_f32(const f32x4 acc[4][4],
        const float* __restrict__ bias, float* __restrict__ ob,
        int p0, int wv, int lane)
{
    const int pl = p0 + (lane & 15);
    #pragma unroll
    for (int i = 0; i < 4; ++i)
        #pragma unroll
        for (int r = 0; r < 4; ++r) {
            const int o = wv * 64 + i * 16 + (lane >> 4) * 4 + r;
            const float bz = bias[o];
            #pragma unroll
            for (int f = 0; f < 4; ++f)
                ob[(size_t)o * HWI + pl + f * 16] = acc[i][f][r] + bz;
        }
}

__device__ __forceinline__ void conv_epi_bf16(const f32x4 acc[4][4],
        const float* __restrict__ bias, unsigned short* __restrict__ ob,
        int p0, int wv, int lane)
{
    const int pl = p0 + (lane & 15);
    #pragma unroll
    for (int i = 0; i < 4; ++i)
        #pragma unroll
        for (int r = 0; r < 4; ++r) {
            const int o = wv * 64 + i * 16 + (lane >> 4) * 4 + r;
            const float bz = bias[o];
            #pragma unroll
            for (int f = 0; f < 4; ++f)
                ob[(size_t)o * HWI + pl + f * 16] = f2bf(acc[i][f][r] + bz);
        }
}

__device__ __forceinline__ void conv_epi_pair(const f32x4 acc[4][4],
        const float* __restrict__ bias, unsigned short* __restrict__ oh,
        unsigned short* __restrict__ ol, int p0, int wv, int lane)
{
    const int pl = p0 + (lane & 15);
    #pragma unroll
    for (int i = 0; i < 4; ++i)
        #pragma unroll
        for (int r = 0; r < 4; ++r) {
            const int o = wv * 64 + i * 16 + (lane >> 4) * 4 + r;
            const float bz = bias[o];
            #pragma unroll
            for (int f = 0; f < 4; ++f) {
                const size_t off = (size_t)o * HWI + pl + f * 16;
                const float val = acc[i][f][r] + bz;
                unsigned short hb = f2bf(val);
                oh[off] = hb;
                ol[off] = f2bf(val - bf2f(hb));
            }
        }
}

// ---------------------------------------------------------------------------
// Fused q,v,k convs (fp32 in, bf16x3 MFMA). f1,f2 out as bf16 hi/lo pairs,
// g1 out bf16. Same staging/pipeline as round-7 convN. grid: (HWI/64, B_)
// ---------------------------------------------------------------------------
__global__ __launch_bounds__(256)
void convQVK_k(const float* __restrict__ in, const short* __restrict__ wb,
               const float* __restrict__ b0, const float* __restrict__ b1,
               const float* __restrict__ b2,
               unsigned short* __restrict__ f1h, unsigned short* __restrict__ f1l,
               unsigned short* __restrict__ f2h, unsigned short* __restrict__ f2l,
               unsigned short* __restrict__ g1b)
{
    __shared__ short xh[64][256];
    __shared__ short xl[64][256];

    const int tid  = threadIdx.x;
    const int lane = tid & 63;
    const int wv   = tid >> 6;

    const int id    = blockIdx.y * gridDim.x + blockIdx.x;
    const int chunk = (gridDim.x * gridDim.y) >> 3;
    const int nid   = (id & 7) * chunk + (id >> 3);
    const int p0    = (nid & 63) * 64;
    const int b     = nid >> 6;

    const float* inb = in + (size_t)b * C_ * HWI + p0;
    const int sp = tid & 63, kq = tid >> 6;

    float v[32];
    stage_load(inb, 0, sp, kq, v);
    stage_write(0, sp, kq, v, xh, xl);
    __syncthreads();

    const int o16b = wv * 4;
    const size_t obase = (size_t)b * C_ * HWI;

    // conv0 (q -> f1 pair) with split-stage overlap
    stage_load(inb, 1, sp, kq, v);
    f32x4 acc[4][4] = {};
    #pragma unroll
    for (int s = 0; s < 4; ++s)
        conv_step(s, lane, o16b, wb, wb + NW, xh, xl, acc);
    stage_write(1, sp, kq, v, xh, xl);
    __syncthreads();
    #pragma unroll
    for (int s = 4; s < 8; ++s)
        conv_step(s, lane, o16b, wb, wb + NW, xh, xl, acc);
    conv_epi_pair(acc, b0, f1h + obase, f1l + obase, p0, wv, lane);

    // conv1 (v -> f2 pair)
    {
        const short* wh = wb + 2 * (size_t)NW;
        f32x4 acc2[4][4] = {};
        #pragma unroll 2
        for (int s = 0; s < 8; ++s)
            conv_step(s, lane, o16b, wh, wh + NW, xh, xl, acc2);
        conv_epi_pair(acc2, b1, f2h + obase, f2l + obase, p0, wv, lane);
    }

    // conv2 (k -> g1 bf16)
    {
        const short* wh = wb + 4 * (size_t)NW;
        f32x4 acc3[4][4] = {};
        #pragma unroll 2
        for (int s = 0; s < 8; ++s)
            conv_step(s, lane, o16b, wh, wh + NW, xh, xl, acc3);
        conv_epi_bf16(acc3, b2, g1b + obase, p0, wv, lane);
    }
}

// ---------------------------------------------------------------------------
// Generic convN (round-7) kept for the small-ws fallback path
// ---------------------------------------------------------------------------
template<int NOUT, bool G1B>
__global__ __launch_bounds__(256)
void convN_k(const float* __restrict__ in, const short* __restrict__ wb,
             const float* __restrict__ b0, const float* __restrict__ b1,
             const float* __restrict__ b2,
             void* o0, void* o1, void* o2)
{
    __shared__ short xh[64][256];
    __shared__ short xl[64][256];

    const int tid  = threadIdx.x;
    const int lane = tid & 63;
    const int wv   = tid >> 6;

    const int id    = blockIdx.y * gridDim.x + blockIdx.x;
    const int chunk = (gridDim.x * gridDim.y) >> 3;
    const int nid   = (id & 7) * chunk + (id >> 3);
    const int p0    = (nid & 63) * 64;
    const int b     = nid >> 6;

    const float* inb = in + (size_t)b * C_ * HWI + p0;
    const int sp = tid & 63, kq = tid >> 6;

    float v[32];
    stage_load(inb, 0, sp, kq, v);
    stage_write(0, sp, kq, v, xh, xl);
    __syncthreads();

    const int o16b = wv * 4;
    const size_t obase = (size_t)b * C_ * HWI;

    stage_load(inb, 1, sp, kq, v);
    f32x4 acc[4][4] = {};
    #pragma unroll
    for (int s = 0; s < 4; ++s)
        conv_step(s, lane, o16b, wb, wb + NW, xh, xl, acc);
    stage_write(1, sp, kq, v, xh, xl);
    __syncthreads();
    #pragma unroll
    for (int s = 4; s < 8; ++s)
        conv_step(s, lane, o16b, wb, wb + NW, xh, xl, acc);

    if (G1B && NOUT == 1)
        conv_epi_bf16(acc, b0, (unsigned short*)o0 + obase, p0, wv, lane);
    else
        conv_epi_f32(acc, b0, (float*)o0 + obase, p0, wv, lane);

    #pragma unroll
    for (int cv = 1; cv < NOUT; ++cv) {
        const short* wh   = wb + (size_t)cv * 2 * NW;
        const float* bias = (cv == 1) ? b1 : b2;
        void*        op   = (cv == 1) ? o1 : o2;
        f32x4 acc2[4][4] = {};
        #pragma unroll 2
        for (int s = 0; s < 8; ++s)
            conv_step(s, lane, o16b, wh, wh + NW, xh, xl, acc2);
        if (G1B && cv == NOUT - 1)
            conv_epi_bf16(acc2, bias, (unsigned short*)op + obase, p0, wv, lane);
        else
            conv_epi_f32(acc2, bias, (float*)op + obase, p0, wv, lane);
    }
}

// ---------------------------------------------------------------------------
// Final conv: bf16 input, 2-term MFMA, +bias +residual -> fp32. 32 KB LDS.
// ---------------------------------------------------------------------------
__global__ __launch_bounds__(256, 3)
void convY_k(const unsigned short* __restrict__ in, const float* __restrict__ res,
             const short* __restrict__ wh, const short* __restrict__ wl,
             const float* __restrict__ bias, float* __restrict__ out)
{
    __shared__ short ys[64][256];

    const int tid  = threadIdx.x;
    const int lane = tid & 63;
    const int wv   = tid >> 6;

    const int id    = blockIdx.y * gridDim.x + blockIdx.x;
    const int chunk = (gridDim.x * gridDim.y) >> 3;
    const int nid   = (id & 7) * chunk + (id >> 3);
    const int p0    = (nid & 63) * 64;
    const int b     = nid >> 6;

    const unsigned short* inb = in + (size_t)b * C_ * HWI + p0;
    const int sp = tid & 63, kq = tid >> 6;

    unsigned short uv[32];

    #pragma unroll
    for (int r = 0; r < 4; ++r) {
        const int k8 = r * 4 + kq;
        #pragma unroll
        for (int j = 0; j < 8; ++j) uv[r * 8 + j] = inb[(size_t)(k8 * 8 + j) * HWI + sp];
    }
    #pragma unroll
    for (int r = 0; r < 4; ++r) {
        const int k8 = r * 4 + kq;
        short8 v8;
        #pragma unroll
        for (int j = 0; j < 8; ++j) v8[j] = (short)uv[r * 8 + j];
        *(short8*)&ys[sp][(k8 ^ (sp & 7)) * 8] = v8;
    }
    __syncthreads();

    #pragma unroll
    for (int r = 0; r < 4; ++r) {
        const int k8 = 16 + r * 4 + kq;
        #pragma unroll
        for (int j = 0; j < 8; ++j) uv[r * 8 + j] = inb[(size_t)(k8 * 8 + j) * HWI + sp];
    }

    const int o16b = wv * 4;
    f32x4 acc[4][4] = {};

    #pragma unroll
    for (int s = 0; s < 4; ++s) {
        const int k8 = s * 4 + (lane >> 4);
        short8 ah[4], al[4], bh[4];
        #pragma unroll
        for (int i = 0; i < 4; ++i) {
            const int aoff = ((o16b + i) * 32 + k8) * 128 + (lane & 15) * 8;
            ah[i] = *(const short8*)(wh + aoff);
            al[i] = *(const short8*)(wl + aoff);
        }
        #pragma unroll
        for (int f = 0; f < 4; ++f) {
            const int pr = f * 16 + (lane & 15);
            bh[f] = *(const short8*)&ys[pr][(k8 ^ (pr & 7)) * 8];
        }
        __builtin_amdgcn_s_setprio(1);
        #pragma unroll
        for (int i = 0; i < 4; ++i)
            #pragma unroll
            for (int f = 0; f < 4; ++f) {
                acc[i][f] = MFMA(ah[i], bh[f], acc[i][f]);
                acc[i][f] = MFMA(al[i], bh[f], acc[i][f]);
            }
        __builtin_amdgcn_s_setprio(0);
    }

    #pragma unroll
    for (int r = 0; r < 4; ++r) {
        const int k8 = 16 + r * 4 + kq;
        short8 v8;
        #pragma unroll
        for (int j = 0; j < 8; ++j) v8[j] = (short)uv[r * 8 + j];
        *(short8*)&ys[sp][(k8 ^ (sp & 7)) * 8] = v8;
    }
    __syncthreads();

    #pragma unroll
    for (int s = 4; s < 8; ++s) {
        const int k8 = s * 4 + (lane >> 4);
        short8 ah[4], al[4], bh[4];
        #pragma unroll
        for (int i = 0; i < 4; ++i) {
            const int aoff = ((o16b + i) * 32 + k8) * 128 + (lane & 15) * 8;
            ah[i] = *(const short8*)(wh + aoff);
            al[i] = *(const short8*)(wl + aoff);
        }
        #pragma unroll
        for (int f = 0; f < 4; ++f) {
            const int pr = f * 16 + (lane & 15);
            bh[f] = *(const short8*)&ys[pr][(k8 ^ (pr & 7)) * 8];
        }
        __builtin_amdgcn_s_setprio(1);
        #pragma unroll
        for (int i = 0; i < 4; ++i)
            #pragma unroll
            for (int f = 0; f < 4; ++f) {
                acc[i][f] = MFMA(ah[i], bh[f], acc[i][f]);
                acc[i][f] = MFMA(al[i], bh[f], acc[i][f]);
            }
        __builtin_amdgcn_s_setprio(0);
    }

    float* ob = out + (size_t)b * C_ * HWI;
    const float* rb = res + (size_t)b * C_ * HWI;
    const int pl = p0 + (lane & 15);
    #pragma unroll
    for (int i = 0; i < 4; ++i)
        #pragma unroll
        for (int r = 0; r < 4; ++r) {
            const int o = wv * 64 + i * 16 + (lane >> 4) * 4 + r;
            const float bz = bias[o];
            #pragma unroll
            for (int f = 0; f < 4; ++f) {
                const size_t off = (size_t)o * HWI + pl + f * 16;
                ob[off] = acc[i][f][r] + bz + rb[off];
            }
        }
}

// ---------------------------------------------------------------------------
// zgemmP: per-(b,c) z = f1 @ f2^T via 3-term bf16 MFMA (hi/lo pairs), fused
// exp epilogue -> P = e^(z-SHIFT) bf16, LDS-transposed coalesced store.
// grid (C_, B_), 256 thr (4 waves), 32 KB LDS.
// ---------------------------------------------------------------------------
__global__ __launch_bounds__(256)
void zgemmP_k(const unsigned short* __restrict__ f1h, const unsigned short* __restrict__ f1l,
              const unsigned short* __restrict__ f2h, const unsigned short* __restrict__ f2l,
              unsigned short* __restrict__ P)
{
    __shared__ short a_h[64 * 64], a_l[64 * 64], bm_h[64 * 64], bm_l[64 * 64];

    const int tid = threadIdx.x, lane = tid & 63, wv = tid >> 6;
    const int c = blockIdx.x, b = blockIdx.y;
    const size_t base = ((size_t)b * C_ + c) * HWI;

    const int r = tid >> 2, q8 = (tid & 3) * 2;
    {
        const size_t g0 = base + r * 64 + q8 * 8;
        short8 vh0 = *(const short8*)(f1h + g0), vh1 = *(const short8*)(f1h + g0 + 8);
        short8 vl0 = *(const short8*)(f1l + g0), vl1 = *(const short8*)(f1l + g0 + 8);
        short8 uh0 = *(const short8*)(f2h + g0), uh1 = *(const short8*)(f2h + g0 + 8);
        short8 ul0 = *(const short8*)(f2l + g0), ul1 = *(const short8*)(f2l + g0 + 8);
        const int c0 = (q8 ^ (r & 7)) * 8, c1 = ((q8 + 1) ^ (r & 7)) * 8;
        *(short8*)&a_h[r * 64 + c0] = vh0;  *(short8*)&a_h[r * 64 + c1] = vh1;
        *(short8*)&a_l[r * 64 + c0] = vl0;  *(short8*)&a_l[r * 64 + c1] = vl1;
        *(short8*)&bm_h[r * 64 + c0] = uh0; *(short8*)&bm_h[r * 64 + c1] = uh1;
        *(short8*)&bm_l[r * 64 + c0] = ul0; *(short8*)&bm_l[r * 64 + c1] = ul1;
    }
    __syncthreads();

    f32x4 acc[4] = {};
    const int m = wv * 16 + (lane & 15);
    #pragma unroll
    for (int s = 0; s < 2; ++s) {
        const int k8 = s * 4 + (lane >> 4);
        short8 ah = *(const short8*)&a_h[m * 64 + (k8 ^ (m & 7)) * 8];
        short8 al = *(const short8*)&a_l[m * 64 + (k8 ^ (m & 7)) * 8];
        #pragma unroll
        for (int nf = 0; nf < 4; ++nf) {
            const int n = nf * 16 + (lane & 15);
            short8 bh = *(const short8*)&bm_h[n * 64 + (k8 ^ (n & 7)) * 8];
            short8 bl = *(const short8*)&bm_l[n * 64 + (k8 ^ (n & 7)) * 8];
            acc[nf] = MFMA(ah, bh, acc[nf]);
            acc[nf] = MFMA(al, bh, acc[nf]);
            acc[nf] = MFMA(ah, bl, acc[nf]);
        }
    }
    __syncthreads();   // all frag reads done; reuse a_h as transpose buffer

    short* pt = a_h;
    #pragma unroll
    for (int nf = 0; nf < 4; ++nf)
        #pragma unroll
        for (int rr = 0; rr < 4; ++rr) {
            const int h = wv * 16 + (lane >> 4) * 4 + rr;
            const int g = nf * 16 + (lane & 15);
            const float pv = __expf(acc[nf][rr] - SHIFT);
            pt[h * 64 + (((g >> 3) ^ (h & 7)) * 8) + (g & 7)] = (short)f2bf(pv);
        }
    __syncthreads();
    {
        const size_t g0 = base + r * 64 + q8 * 8;
        const int c0 = (q8 ^ (r & 7)) * 8, c1 = ((q8 + 1) ^ (r & 7)) * 8;
        *(short8*)(P + g0)     = *(const short8*)&pt[r * 64 + c0];
        *(short8*)(P + g0 + 8) = *(const short8*)&pt[r * 64 + c1];
    }
}

// ---------------------------------------------------------------------------
// statsP: sr[b,p] = 1 / sum_c P[b,c,p]   (P bf16, no exp)
// ---------------------------------------------------------------------------
__global__ __launch_bounds__(256)
void statsP_k(const unsigned short* __restrict__ P, float* __restrict__ sr)
{
    const int qidx = blockIdx.x * 256 + threadIdx.x;
    const int b = qidx >> 12, p = qidx & 4095;
    const unsigned short* pp = P + (size_t)b * C_ * HWI + p;
    float s = 0.f;
    for (int c0 = 0; c0 < C_; c0 += 8) {
        float e = 0.f;
        #pragma unroll
        for (int j = 0; j < 8; ++j) e += bf2f(pp[(size_t)(c0 + j) * HWI]);
        s += e;
    }
    sr[qidx] = 1.0f / s;
}

// ---------------------------------------------------------------------------
// pvP: out1 = (P .* sr) @ g1 via single-term bf16 MFMA. sr folded at
// A-staging; g1 transposed at B-staging. grid (C_, B_), 16 KB LDS.
// ---------------------------------------------------------------------------
__global__ __launch_bounds__(256)
void pvP_k(const unsigned short* __restrict__ P, const float* __restrict__ sr,
           const unsigned short* __restrict__ g1, unsigned short* __restrict__ out1)
{
    __shared__ short pa[64 * 64], gb[64 * 64];

    const int tid = threadIdx.x, lane = tid & 63, wv = tid >> 6;
    const int c = blockIdx.x, b = blockIdx.y;
    const size_t base = ((size_t)b * C_ + c) * HWI;

    const int r = tid >> 2, q8 = (tid & 3) * 2;
    {   // A = P' = P * sr   [h][g]
        const size_t g0 = base + r * 64 + q8 * 8;
        const float* srp = sr + (size_t)b * HWI + r * 64 + q8 * 8;
        short8 p0 = *(const short8*)(P + g0), p1 = *(const short8*)(P + g0 + 8);
        short8 w0, w1;
        #pragma unroll
        for (int j = 0; j < 8; ++j) {
            w0[j] = (short)f2bf(bf2f((unsigned short)p0[j]) * srp[j]);
            w1[j] = (short)f2bf(bf2f((unsigned short)p1[j]) * srp[8 + j]);
        }
        const int c0 = (q8 ^ (r & 7)) * 8, c1 = ((q8 + 1) ^ (r & 7)) * 8;
        *(short8*)&pa[r * 64 + c0] = w0;
        *(short8*)&pa[r * 64 + c1] = w1;
    }
    {   // B = g1^T : gb[w][g]
        const int w = tid & 63, kq = tid >> 6;
        short8 t0, t1;
        #pragma unroll
        for (int j = 0; j < 8; ++j) t0[j] = (short)g1[base + (size_t)(kq * 16 + j) * 64 + w];
        #pragma unroll
        for (int j = 0; j < 8; ++j) t1[j] = (short)g1[base + (size_t)(kq * 16 + 8 + j) * 64 + w];
        const int c0 = ((kq * 2) ^ (w & 7)) * 8, c1 = ((kq * 2 + 1) ^ (w & 7)) * 8;
        *(short8*)&gb[w * 64 + c0] = t0;
        *(short8*)&gb[w * 64 + c1] = t1;
    }
    __syncthreads();

    f32x4 acc[4] = {};
    const int m = wv * 16 + (lane & 15);
    #pragma unroll
    for (int s = 0; s < 2; ++s) {
        const int k8 = s * 4 + (lane >> 4);
        short8 aa = *(const short8*)&pa[m * 64 + (k8 ^ (m & 7)) * 8];
        #pragma unroll
        for (int nf = 0; nf < 4; ++nf) {
            const int n = nf * 16 + (lane & 15);
            short8 bb = *(const short8*)&gb[n * 64 + (k8 ^ (n & 7)) * 8];
            acc[nf] = MFMA(aa, bb, acc[nf]);
        }
    }
    __syncthreads();

    short* ot = pa;
    #pragma unroll
    for (int nf = 0; nf < 4; ++nf)
        #pragma unroll
        for (int rr = 0; rr < 4; ++rr) {
            const int h = wv * 16 + (lane >> 4) * 4 + rr;
            const int w = nf * 16 + (lane & 15);
            ot[h * 64 + (((w >> 3) ^ (h & 7)) * 8) + (w & 7)] = (short)f2bf(acc[nf][rr]);
        }
    __syncthreads();
    {
        const size_t g0 = base + r * 64 + q8 * 8;
        const int c0 = (q8 ^ (r & 7)) * 8, c1 = ((q8 + 1) ^ (r & 7)) * 8;
        *(short8*)(out1 + g0)     = *(const short8*)&ot[r * 64 + c0];
        *(short8*)(out1 + g0 + 8) = *(const short8*)&ot[r * 64 + c1];
    }
}

// ---------------------------------------------------------------------------
// old middle kernels kept for small-ws fallback
// ---------------------------------------------------------------------------
__global__ __launch_bounds__(256)
void zgemm_k(const float* f1, const float* __restrict__ f2, float* z)
{
    __shared__ float aT[64][64];
    __shared__ float bT[64][64];

    const int tid = threadIdx.x;
    const int c = blockIdx.x, b = blockIdx.y;
    const size_t base = ((size_t)b * C_ + c) * HWI;

    const int r = tid >> 2;
    const int q = (tid & 3) << 4;
    {
        const float* pa = f1 + base + (size_t)r * HDIM + q;
        const float* pb = f2 + base + (size_t)r * HDIM + q;
        float4 v0 = *(const float4*)(pa + 0);
        float4 v1 = *(const float4*)(pa + 4);
        float4 v2 = *(const float4*)(pa + 8);
        float4 v3 = *(const float4*)(pa + 12);
        float4 u0 = *(const float4*)(pb + 0);
        float4 u1 = *(const float4*)(pb + 4);
        float4 u2 = *(const float4*)(pb + 8);
        float4 u3 = *(const float4*)(pb + 12);
        float ta[16] = {v0.x,v0.y,v0.z,v0.w, v1.x,v1.y,v1.z,v1.w,
                        v2.x,v2.y,v2.z,v2.w, v3.x,v3.y,v3.z,v3.w};
        float tb[16] = {u0.x,u0.y,u0.z,u0.w, u1.x,u1.y,u1.z,u1.w,
                        u2.x,u2.y,u2.z,u2.w, u3.x,u3.y,u3.z,u3.w};
        #pragma unroll
        for (int j = 0; j < 16; ++j) { aT[q + j][r] = ta[j]; bT[q + j][r] = tb[j]; }
    }
    __syncthreads();

    const int tx = tid & 15, ty = tid >> 4;
    float acc[4][4] = {};
    #pragma unroll 8
    for (int w = 0; w < 64; ++w) {
        float4 a = *(const float4*)&aT[w][ty * 4];
        float4 g = *(const float4*)&bT[w][tx * 4];
        float av[4] = {a.x, a.y, a.z, a.w};
        float gv[4] = {g.x, g.y, g.z, g.w};
        #pragma unroll
        for (int i = 0; i < 4; ++i)
            #pragma unroll
            for (int j = 0; j < 4; ++j)
                acc[i][j] += av[i] * gv[j];
    }

    float* zb = z + base;
    #pragma unroll
    for (int i = 0; i < 4; ++i)
        *(float4*)&zb[(size_t)(ty * 4 + i) * HDIM + tx * 4] =
            make_float4(acc[i][0], acc[i][1], acc[i][2], acc[i][3]);
}

__global__ __launch_bounds__(256)
void stats_k(const float* __restrict__ z, float* __restrict__ sr)
{
    const int qidx = blockIdx.x * 256 + threadIdx.x;
    const int b = qidx >> 12, p = qidx & 4095;
    const float* zp = z + (size_t)b * C_ * HWI + p;
    float s = 0.f;
    for (int c0 = 0; c0 < C_; c0 += 8) {
        float v[8];
        #pragma unroll
        for (int j = 0; j < 8; ++j) v[j] = zp[(size_t)(c0 + j) * HWI];
        float e = 0.f;
        #pragma unroll
        for (int j = 0; j < 8; ++j) e += __expf(v[j] - SHIFT);
        s += e;
    }
    sr[qidx] = 1.0f / s;
}

__global__ __launch_bounds__(256)
void pvgemm_k(const float* __restrict__ z, const float* __restrict__ sr,
              const unsigned short* __restrict__ g1,
              unsigned short* __restrict__ out1)
{
    __shared__ float pT[64][64];
    __shared__ float gl[64][64];

    const int tid = threadIdx.x;
    const int c = blockIdx.x, b = blockIdx.y;
    const size_t base = ((size_t)b * C_ + c) * HWI;

    const int r = tid >> 2;
    const int q = (tid & 3) << 4;
    {
        const float* zp = z  + base + (size_t)r * HDIM + q;
        const float* rp = sr + (size_t)b * HWI + (size_t)r * HDIM + q;
        const unsigned short* gp = g1 + base + (size_t)r * HDIM + q;
        float pv[16], gv[16];
        #pragma unroll
        for (int j = 0; j < 4; ++j) {
            float4 zv = *(const float4*)(zp + j * 4);
            float4 rv = *(const float4*)(rp + j * 4);
            pv[j*4+0] = __expf(zv.x - SHIFT) * rv.x;
            pv[j*4+1] = __expf(zv.y - SHIFT) * rv.y;
            pv[j*4+2] = __expf(zv.z - SHIFT) * rv.z;
            pv[j*4+3] = __expf(zv.w - SHIFT) * rv.w;
        }
        short8 ga = *(const short8*)(gp + 0);
        short8 gb = *(const short8*)(gp + 8);
        #pragma unroll
        for (int j = 0; j < 8; ++j) { gv[j] = bf2f((unsigned short)ga[j]); gv[8 + j] = bf2f((unsigned short)gb[j]); }
        #pragma unroll
        for (int j = 0; j < 16; ++j) { pT[q + j][r] = pv[j]; gl[r][q + j] = gv[j]; }
    }
    __syncthreads();

    const int tx = tid & 15, ty = tid >> 4;
    float acc[4][4] = {};
    #pragma unroll 8
    for (int g = 0; g < 64; ++g) {
        float4 a = *(const float4*)&pT[g][ty * 4];
        float4 vv4 = *(const float4*)&gl[g][tx * 4];
        float av[4] = {a.x, a.y, a.z, a.w};
        float vv[4] = {vv4.x, vv4.y, vv4.z, vv4.w};
        #pragma unroll
        for (int i = 0; i < 4; ++i)
            #pragma unroll
            for (int j = 0; j < 4; ++j)
                acc[i][j] += av[i] * vv[j];
    }

    unsigned short* ob = out1 + base;
    #pragma unroll
    for (int i = 0; i < 4; ++i) {
        s4v w;
        #pragma unroll
        for (int j = 0; j < 4; ++j) w[j] = (short)f2bf(acc[i][j]);
        *(s4v*)&ob[(size_t)(ty * 4 + i) * HDIM + tx * 4] = w;
    }
}

// ---------------------------------------------------------------------------
extern "C" void kernel_launch(void* const* d_in, const int* in_sizes, int n_in,
                              void* d_out, int out_size, void* d_ws, size_t ws_size,
                              hipStream_t stream)
{
    (void)in_sizes; (void)n_in; (void)out_size;
    const float* x  = (const float*)d_in[0];
    const float* wq = (const float*)d_in[1];
    const float* bq = (const float*)d_in[2];
    const float* wv = (const float*)d_in[3];
    const float* bv = (const float*)d_in[4];
    const float* wk = (const float*)d_in[5];
    const float* bk = (const float*)d_in[6];
    const float* wy = (const float*)d_in[7];
    const float* by = (const float*)d_in[8];
    float* out = (float*)d_out;

    const size_t N  = (size_t)B_ * C_ * HWI;   // 33,554,432
    const size_t NS = (size_t)B_ * HWI;        // 131,072

    char* wsb = (char*)d_ws;
    short* wsp = (short*)wsb;
    const size_t wbytes = 8 * (size_t)NW * sizeof(short);   // 1 MB
    char* fb = wsb + wbytes;

    dim3 blk(256);
    hipLaunchKernelGGL(wsplit4_k, dim3(32, 4), blk, 0, stream, wq, wv, wk, wy, wsp);
    const short* wqvk = wsp;
    const short* why  = wsp + 6 * NW;
    const short* wly  = wsp + 7 * NW;

    dim3 cgrid(HWI / 64, B_);     // 2048 blocks
    dim3 zgrid(C_, B_);           // 8192 blocks
    dim3 sgrid((unsigned)(NS / 256));

    const bool bigws = ws_size >= wbytes + 8 * N + 4 * NS;

    if (bigws) {
        // ws: f1h | f1l | g1b | P (bf16, 2N bytes each) | sr (NS f32)
        // d_out: f2h | f2l (bf16, dead after zgemmP; convY overwrites)
        unsigned short* f1h = (unsigned short*)fb;
        unsigned short* f1l = (unsigned short*)(fb + 2 * N);
        unsigned short* g1b = (unsigned short*)(fb + 4 * N);
        unsigned short* P   = (unsigned short*)(fb + 6 * N);
        float*          sr  = (float*)(fb + 8 * N);
        unsigned short* f2h = (unsigned short*)d_out;
        unsigned short* f2l = f2h + N;
        unsigned short* o1b = f1h;   // reuse (f1 dead after zgemmP)

        hipLaunchKernelGGL(convQVK_k, cgrid, blk, 0, stream,
                           x, wqvk, bq, bv, bk, f1h, f1l, f2h, f2l, g1b);
        hipLaunchKernelGGL(zgemmP_k, zgrid, blk, 0, stream, f1h, f1l, f2h, f2l, P);
        hipLaunchKernelGGL(statsP_k, sgrid, blk, 0, stream, P, sr);
        hipLaunchKernelGGL(pvP_k,    zgrid, blk, 0, stream, P, sr, g1b, o1b);
        hipLaunchKernelGGL(convY_k,  cgrid, blk, 0, stream, o1b, x, why, wly, by, out);
    } else {
        // fallback: round-7 small-ws path
        float*          f2  = (float*)fb;
        unsigned short* g1b = (unsigned short*)fb;
        unsigned short* o1b = (unsigned short*)fb + N;
        float*          sr  = (float*)(fb + 4 * N);
        hipLaunchKernelGGL((convN_k<2, false>), cgrid, blk, 0, stream,
                           x, wqvk, bq, bv, (const float*)0, out, f2, (void*)0);
        hipLaunchKernelGGL(zgemm_k,  zgrid, blk, 0, stream, out, f2, out);
        hipLaunchKernelGGL(stats_k,  sgrid, blk, 0, stream, out, sr);
        hipLaunchKernelGGL((convN_k<1, true>), cgrid, blk, 0, stream,
                           x, wqvk + 4 * (size_t)NW, bk, (const float*)0, (const float*)0,
                           g1b, (void*)0, (void*)0);
        hipLaunchKernelGGL(pvgemm_k, zgrid, blk, 0, stream, out, sr, g1b, o1b);
        hipLaunchKernelGGL(convY_k,  cgrid, blk, 0, stream, o1b, x, why, wly, by, out);
    }
}

// Round 10
// 333.635 us; speedup vs baseline: 1.6726x; 1.1395x over previous
//
#include <hip/hip_runtime.h>
#include <hip/hip_bf16.h>

#define B_    32
#define C_    256
#define HWI   4096   // 64*64
#define HDIM  64
#define NW    65536  // elems per weight matrix (256x256)
#define SHIFT 20.0f  // fixed softmax shift

typedef short short8 __attribute__((ext_vector_type(8)));
typedef short s4v    __attribute__((ext_vector_type(4)));
typedef float f32x4  __attribute__((ext_vector_type(4)));
typedef _Float16 half8 __attribute__((ext_vector_type(8)));

#define MFMAH(a, b, c) __builtin_amdgcn_mfma_f32_16x16x32_f16(a, b, c, 0, 0, 0)

// fp16 helpers (RNE casts)
__device__ __forceinline__ unsigned short f2h(float x) {
    _Float16 t = (_Float16)x;
    return __builtin_bit_cast(unsigned short, t);
}
__device__ __forceinline__ float h2f(unsigned short b) {
    return (float)__builtin_bit_cast(_Float16, b);
}
// fp32 -> fp16 hi + fp16 lo (lo rounds exact remainder; self-correcting)
__device__ __forceinline__ void f2h_pair(float x, short& h, short& l) {
    unsigned short hb = f2h(x);
    h = (short)hb;
    l = (short)f2h(x - h2f(hb));
}
// bf16 (for P only — needs > fp16 range)
__device__ __forceinline__ unsigned short f2bf(float x) {
    __hip_bfloat16 t = __float2bfloat16(x);
    return *reinterpret_cast<unsigned short*>(&t);
}
__device__ __forceinline__ float bf2f(unsigned short b) {
    return __uint_as_float((unsigned)b << 16);
}

// ---------------------------------------------------------------------------
// Pre-split ALL 4 weight matrices fp32 -> fp16 hi/lo, MFMA-fragment-linear:
// flat = (o>>4)*4096 + (k>>3)*128 + (o&15)*8 + (k&7). grid (32, 4)
// ---------------------------------------------------------------------------
__global__ __launch_bounds__(256)
void wsplit4_k(const float* __restrict__ w0, const float* __restrict__ w1,
               const float* __restrict__ w2, const float* __restrict__ w3,
               short* __restrict__ dst)
{
    const int m = blockIdx.y;
    const float* w = (m == 0) ? w0 : (m == 1) ? w1 : (m == 2) ? w2 : w3;
    short* wh = dst + (size_t)m * 2 * NW;
    short* wl = wh + NW;

    const int g  = blockIdx.x * 256 + threadIdx.x;
    const int o  = g >> 5, k8 = g & 31;
    const float* src = w + o * 256 + k8 * 8;
    const int d = (o >> 4) * 4096 + k8 * 128 + (o & 15) * 8;
    short8 h8, l8;
    #pragma unroll
    for (int j = 0; j < 8; ++j) { short h, l; f2h_pair(src[j], h, l); h8[j] = h; l8[j] = l; }
    *(short8*)(wh + d) = h8;
    *(short8*)(wl + d) = l8;
}

// ---------------------------------------------------------------------------
// conv building blocks (proven round-7/9 structure, fp16)
// ---------------------------------------------------------------------------
__device__ __forceinline__ void stage_load(const float* __restrict__ inb,
                                           int half, int sp, int kq, float* v)
{
    #pragma unroll
    for (int r = 0; r < 4; ++r) {
        const int k8 = half * 16 + r * 4 + kq;
        const float* gx = inb + (size_t)(k8 * 8) * HWI + sp;
        #pragma unroll
        for (int j = 0; j < 8; ++j) v[r * 8 + j] = gx[(size_t)j * HWI];
    }
}

__device__ __forceinline__ void stage_write(int half, int sp, int kq,
        const float* v, short (*xh)[256], short (*xl)[256])
{
    #pragma unroll
    for (int r = 0; r < 4; ++r) {
        const int k8 = half * 16 + r * 4 + kq;
        short8 h8, l8;
        #pragma unroll
        for (int j = 0; j < 8; ++j) {
            short h, l; f2h_pair(v[r * 8 + j], h, l); h8[j] = h; l8[j] = l;
        }
        const int ch = (k8 ^ (sp & 7)) * 8;
        *(short8*)&xh[sp][ch] = h8;
        *(short8*)&xl[sp][ch] = l8;
    }
}

__device__ __forceinline__ void conv_step(int s, int lane, int o16b,
        const short* __restrict__ wh, const short* __restrict__ wl,
        const short (*xh)[256], const short (*xl)[256], f32x4 acc[4][4])
{
    const int k8 = s * 4 + (lane >> 4);
    half8 ah[4], al[4], bh[4], bl[4];
    #pragma unroll
    for (int i = 0; i < 4; ++i) {
        const int aoff = ((o16b + i) * 32 + k8) * 128 + (lane & 15) * 8;
        ah[i] = *(const half8*)(wh + aoff);
        al[i] = *(const half8*)(wl + aoff);
    }
    #pragma unroll
    for (int f = 0; f < 4; ++f) {
        const int pr = f * 16 + (lane & 15);
        const int ch = (k8 ^ (pr & 7)) * 8;
        bh[f] = *(const half8*)&xh[pr][ch];
        bl[f] = *(const half8*)&xl[pr][ch];
    }
    __builtin_amdgcn_s_setprio(1);
    #pragma unroll
    for (int i = 0; i < 4; ++i)
        #pragma unroll
        for (int f = 0; f < 4; ++f) {
            acc[i][f] = MFMAH(ah[i], bh[f], acc[i][f]);
            acc[i][f] = MFMAH(al[i], bh[f], acc[i][f]);
            acc[i][f] = MFMAH(ah[i], bl[f], acc[i][f]);
        }
    __builtin_amdgcn_s_setprio(0);
}

__device__ __forceinline__ void conv_epi_f32(const f32x4 acc[4][4],
        const float* __restrict__ bias, float* __restrict__ ob,
        int p0, int wv, int lane)
{
    const int pl = p0 + (lane & 15);
    #pragma unroll
    for (int i = 0; i < 4; ++i)
        #pragma unroll
        for (int r = 0; r < 4; ++r) {
            const int o = wv * 64 + i * 16 + (lane >> 4) * 4 + r;
            const float bz = bias[o];
            #pragma unroll
            for (int f = 0; f < 4; ++f)
                ob[(size_t)o * HWI + pl + f * 16] = acc[i][f][r] + bz;
        }
}

__device__ __forceinline__ void conv_epi_h16(const f32x4 acc[4][4],
        const float* __restrict__ bias, unsigned short* __restrict__ ob,
        int p0, int wv, int lane)
{
    const int pl = p0 + (lane & 15);
    #pragma unroll
    for (int i = 0; i < 4; ++i)
        #pragma unroll
        for (int r = 0; r < 4; ++r) {
            const int o = wv * 64 + i * 16 + (lane >> 4) * 4 + r;
            const float bz = bias[o];
            #pragma unroll
            for (int f = 0; f < 4; ++f)
                ob[(size_t)o * HWI + pl + f * 16] = f2h(acc[i][f][r] + bz);
        }
}

// ---------------------------------------------------------------------------
// Fused q,v,k convs (fp32 in, fp16x3 MFMA). f1,f2,g1 out as SINGLE fp16.
// grid: (HWI/64, B_), XCD-chunked swizzle, split-stage pipeline.
// ---------------------------------------------------------------------------
__global__ __launch_bounds__(256)
void convQVK_k(const float* __restrict__ in, const short* __restrict__ wb,
               const float* __restrict__ b0, const float* __restrict__ b1,
               const float* __restrict__ b2,
               unsigned short* __restrict__ f1, unsigned short* __restrict__ f2,
               unsigned short* __restrict__ g1)
{
    __shared__ short xh[64][256];
    __shared__ short xl[64][256];

    const int tid  = threadIdx.x;
    const int lane = tid & 63;
    const int wv   = tid >> 6;

    const int id    = blockIdx.y * gridDim.x + blockIdx.x;
    const int chunk = (gridDim.x * gridDim.y) >> 3;
    const int nid   = (id & 7) * chunk + (id >> 3);
    const int p0    = (nid & 63) * 64;
    const int b     = nid >> 6;

    const float* inb = in + (size_t)b * C_ * HWI + p0;
    const int sp = tid & 63, kq = tid >> 6;

    float v[32];
    stage_load(inb, 0, sp, kq, v);
    stage_write(0, sp, kq, v, xh, xl);
    __syncthreads();

    const int o16b = wv * 4;
    const size_t obase = (size_t)b * C_ * HWI;

    // conv0 (q -> f1) with split-stage overlap
    stage_load(inb, 1, sp, kq, v);
    f32x4 acc[4][4] = {};
    #pragma unroll
    for (int s = 0; s < 4; ++s)
        conv_step(s, lane, o16b, wb, wb + NW, xh, xl, acc);
    stage_write(1, sp, kq, v, xh, xl);
    __syncthreads();
    #pragma unroll
    for (int s = 4; s < 8; ++s)
        conv_step(s, lane, o16b, wb, wb + NW, xh, xl, acc);
    conv_epi_h16(acc, b0, f1 + obase, p0, wv, lane);

    // conv1 (v -> f2)
    {
        const short* wh = wb + 2 * (size_t)NW;
        f32x4 acc2[4][4] = {};
        #pragma unroll 2
        for (int s = 0; s < 8; ++s)
            conv_step(s, lane, o16b, wh, wh + NW, xh, xl, acc2);
        conv_epi_h16(acc2, b1, f2 + obase, p0, wv, lane);
    }

    // conv2 (k -> g1)
    {
        const short* wh = wb + 4 * (size_t)NW;
        f32x4 acc3[4][4] = {};
        #pragma unroll 2
        for (int s = 0; s < 8; ++s)
            conv_step(s, lane, o16b, wh, wh + NW, xh, xl, acc3);
        conv_epi_h16(acc3, b2, g1 + obase, p0, wv, lane);
    }
}

// ---------------------------------------------------------------------------
// Generic convN kept for the small-ws fallback path (fp16 weights/LDS)
// ---------------------------------------------------------------------------
template<int NOUT, bool G1B>
__global__ __launch_bounds__(256)
void convN_k(const float* __restrict__ in, const short* __restrict__ wb,
             const float* __restrict__ b0, const float* __restrict__ b1,
             const float* __restrict__ b2,
             void* o0, void* o1, void* o2)
{
    __shared__ short xh[64][256];
    __shared__ short xl[64][256];

    const int tid  = threadIdx.x;
    const int lane = tid & 63;
    const int wv   = tid >> 6;

    const int id    = blockIdx.y * gridDim.x + blockIdx.x;
    const int chunk = (gridDim.x * gridDim.y) >> 3;
    const int nid   = (id & 7) * chunk + (id >> 3);
    const int p0    = (nid & 63) * 64;
    const int b     = nid >> 6;

    const float* inb = in + (size_t)b * C_ * HWI + p0;
    const int sp = tid & 63, kq = tid >> 6;

    float v[32];
    stage_load(inb, 0, sp, kq, v);
    stage_write(0, sp, kq, v, xh, xl);
    __syncthreads();

    const int o16b = wv * 4;
    const size_t obase = (size_t)b * C_ * HWI;

    stage_load(inb, 1, sp, kq, v);
    f32x4 acc[4][4] = {};
    #pragma unroll
    for (int s = 0; s < 4; ++s)
        conv_step(s, lane, o16b, wb, wb + NW, xh, xl, acc);
    stage_write(1, sp, kq, v, xh, xl);
    __syncthreads();
    #pragma unroll
    for (int s = 4; s < 8; ++s)
        conv_step(s, lane, o16b, wb, wb + NW, xh, xl, acc);

    if (G1B && NOUT == 1)
        conv_epi_h16(acc, b0, (unsigned short*)o0 + obase, p0, wv, lane);
    else
        conv_epi_f32(acc, b0, (float*)o0 + obase, p0, wv, lane);

    #pragma unroll
    for (int cv = 1; cv < NOUT; ++cv) {
        const short* wh   = wb + (size_t)cv * 2 * NW;
        const float* bias = (cv == 1) ? b1 : b2;
        void*        op   = (cv == 1) ? o1 : o2;
        f32x4 acc2[4][4] = {};
        #pragma unroll 2
        for (int s = 0; s < 8; ++s)
            conv_step(s, lane, o16b, wh, wh + NW, xh, xl, acc2);
        if (G1B && cv == NOUT - 1)
            conv_epi_h16(acc2, bias, (unsigned short*)op + obase, p0, wv, lane);
        else
            conv_epi_f32(acc2, bias, (float*)op + obase, p0, wv, lane);
    }
}

// ---------------------------------------------------------------------------
// Final conv: fp16 input, 2-term fp16 MFMA, +bias +residual -> fp32. 32 KB.
// ---------------------------------------------------------------------------
__global__ __launch_bounds__(256, 3)
void convY_k(const unsigned short* __restrict__ in, const float* __restrict__ res,
             const short* __restrict__ wh, const short* __restrict__ wl,
             const float* __restrict__ bias, float* __restrict__ out)
{
    __shared__ short ys[64][256];

    const int tid  = threadIdx.x;
    const int lane = tid & 63;
    const int wv   = tid >> 6;

    const int id    = blockIdx.y * gridDim.x + blockIdx.x;
    const int chunk = (gridDim.x * gridDim.y) >> 3;
    const int nid   = (id & 7) * chunk + (id >> 3);
    const int p0    = (nid & 63) * 64;
    const int b     = nid >> 6;

    const unsigned short* inb = in + (size_t)b * C_ * HWI + p0;
    const int sp = tid & 63, kq = tid >> 6;

    unsigned short uv[32];

    #pragma unroll
    for (int r = 0; r < 4; ++r) {
        const int k8 = r * 4 + kq;
        #pragma unroll
        for (int j = 0; j < 8; ++j) uv[r * 8 + j] = inb[(size_t)(k8 * 8 + j) * HWI + sp];
    }
    #pragma unroll
    for (int r = 0; r < 4; ++r) {
        const int k8 = r * 4 + kq;
        short8 v8;
        #pragma unroll
        for (int j = 0; j < 8; ++j) v8[j] = (short)uv[r * 8 + j];
        *(short8*)&ys[sp][(k8 ^ (sp & 7)) * 8] = v8;
    }
    __syncthreads();

    #pragma unroll
    for (int r = 0; r < 4; ++r) {
        const int k8 = 16 + r * 4 + kq;
        #pragma unroll
        for (int j = 0; j < 8; ++j) uv[r * 8 + j] = inb[(size_t)(k8 * 8 + j) * HWI + sp];
    }

    const int o16b = wv * 4;
    f32x4 acc[4][4] = {};

    #pragma unroll
    for (int s = 0; s < 4; ++s) {
        const int k8 = s * 4 + (lane >> 4);
        half8 ah[4], al[4], bh[4];
        #pragma unroll
        for (int i = 0; i < 4; ++i) {
            const int aoff = ((o16b + i) * 32 + k8) * 128 + (lane & 15) * 8;
            ah[i] = *(const half8*)(wh + aoff);
            al[i] = *(const half8*)(wl + aoff);
        }
        #pragma unroll
        for (int f = 0; f < 4; ++f) {
            const int pr = f * 16 + (lane & 15);
            bh[f] = *(const half8*)&ys[pr][(k8 ^ (pr & 7)) * 8];
        }
        __builtin_amdgcn_s_setprio(1);
        #pragma unroll
        for (int i = 0; i < 4; ++i)
            #pragma unroll
            for (int f = 0; f < 4; ++f) {
                acc[i][f] = MFMAH(ah[i], bh[f], acc[i][f]);
                acc[i][f] = MFMAH(al[i], bh[f], acc[i][f]);
            }
        __builtin_amdgcn_s_setprio(0);
    }

    #pragma unroll
    for (int r = 0; r < 4; ++r) {
        const int k8 = 16 + r * 4 + kq;
        short8 v8;
        #pragma unroll
        for (int j = 0; j < 8; ++j) v8[j] = (short)uv[r * 8 + j];
        *(short8*)&ys[sp][(k8 ^ (sp & 7)) * 8] = v8;
    }
    __syncthreads();

    #pragma unroll
    for (int s = 4; s < 8; ++s) {
        const int k8 = s * 4 + (lane >> 4);
        half8 ah[4], al[4], bh[4];
        #pragma unroll
        for (int i = 0; i < 4; ++i) {
            const int aoff = ((o16b + i) * 32 + k8) * 128 + (lane & 15) * 8;
            ah[i] = *(const half8*)(wh + aoff);
            al[i] = *(const half8*)(wl + aoff);
        }
        #pragma unroll
        for (int f = 0; f < 4; ++f) {
            const int pr = f * 16 + (lane & 15);
            bh[f] = *(const half8*)&ys[pr][(k8 ^ (pr & 7)) * 8];
        }
        __builtin_amdgcn_s_setprio(1);
        #pragma unroll
        for (int i = 0; i < 4; ++i)
            #pragma unroll
            for (int f = 0; f < 4; ++f) {
                acc[i][f] = MFMAH(ah[i], bh[f], acc[i][f]);
                acc[i][f] = MFMAH(al[i], bh[f], acc[i][f]);
            }
        __builtin_amdgcn_s_setprio(0);
    }

    float* ob = out + (size_t)b * C_ * HWI;
    const float* rb = res + (size_t)b * C_ * HWI;
    const int pl = p0 + (lane & 15);
    #pragma unroll
    for (int i = 0; i < 4; ++i)
        #pragma unroll
        for (int r = 0; r < 4; ++r) {
            const int o = wv * 64 + i * 16 + (lane >> 4) * 4 + r;
            const float bz = bias[o];
            #pragma unroll
            for (int f = 0; f < 4; ++f) {
                const size_t off = (size_t)o * HWI + pl + f * 16;
                ob[off] = acc[i][f][r] + bz + rb[off];
            }
        }
}

// ---------------------------------------------------------------------------
// zgemmP: per-(b,c) z = f1 @ f2^T via 1-term fp16 MFMA, fused exp epilogue
// -> P = e^(z-SHIFT) bf16 (range!), LDS-transposed coalesced store.
// grid (C_, B_), 256 thr (4 waves), 16 KB LDS.
// ---------------------------------------------------------------------------
__global__ __launch_bounds__(256)
void zgemmP_k(const unsigned short* __restrict__ f1,
              const unsigned short* __restrict__ f2,
              unsigned short* __restrict__ P)
{
    __shared__ short am[64 * 64], bm[64 * 64];   // 16 KB

    const int tid = threadIdx.x, lane = tid & 63, wv = tid >> 6;
    const int c = blockIdx.x, b = blockIdx.y;
    const size_t base = ((size_t)b * C_ + c) * HWI;

    const int r = tid >> 2, q8 = (tid & 3) * 2;
    {
        const size_t g0 = base + r * 64 + q8 * 8;
        short8 v0 = *(const short8*)(f1 + g0), v1 = *(const short8*)(f1 + g0 + 8);
        short8 u0 = *(const short8*)(f2 + g0), u1 = *(const short8*)(f2 + g0 + 8);
        const int c0 = (q8 ^ (r & 7)) * 8, c1 = ((q8 + 1) ^ (r & 7)) * 8;
        *(short8*)&am[r * 64 + c0] = v0;  *(short8*)&am[r * 64 + c1] = v1;
        *(short8*)&bm[r * 64 + c0] = u0;  *(short8*)&bm[r * 64 + c1] = u1;
    }
    __syncthreads();

    f32x4 acc[4] = {};
    const int m = wv * 16 + (lane & 15);
    #pragma unroll
    for (int s = 0; s < 2; ++s) {
        const int k8 = s * 4 + (lane >> 4);
        half8 a = *(const half8*)&am[m * 64 + (k8 ^ (m & 7)) * 8];
        #pragma unroll
        for (int nf = 0; nf < 4; ++nf) {
            const int n = nf * 16 + (lane & 15);
            half8 bb = *(const half8*)&bm[n * 64 + (k8 ^ (n & 7)) * 8];
            acc[nf] = MFMAH(a, bb, acc[nf]);
        }
    }
    __syncthreads();   // all frag reads done; reuse am as transpose buffer

    short* pt = am;
    #pragma unroll
    for (int nf = 0; nf < 4; ++nf)
        #pragma unroll
        for (int rr = 0; rr < 4; ++rr) {
            const int h = wv * 16 + (lane >> 4) * 4 + rr;
            const int g = nf * 16 + (lane & 15);
            const float pv = __expf(acc[nf][rr] - SHIFT);
            pt[h * 64 + (((g >> 3) ^ (h & 7)) * 8) + (g & 7)] = (short)f2bf(pv);
        }
    __syncthreads();
    {
        const size_t g0 = base + r * 64 + q8 * 8;
        const int c0 = (q8 ^ (r & 7)) * 8, c1 = ((q8 + 1) ^ (r & 7)) * 8;
        *(short8*)(P + g0)     = *(const short8*)&pt[r * 64 + c0];
        *(short8*)(P + g0 + 8) = *(const short8*)&pt[r * 64 + c1];
    }
}

// ---------------------------------------------------------------------------
// statsP: sr[b,p] = 1 / sum_c P[b,c,p]   (P bf16)
// ---------------------------------------------------------------------------
__global__ __launch_bounds__(256)
void statsP_k(const unsigned short* __restrict__ P, float* __restrict__ sr)
{
    const int qidx = blockIdx.x * 256 + threadIdx.x;
    const int b = qidx >> 12, p = qidx & 4095;
    const unsigned short* pp = P + (size_t)b * C_ * HWI + p;
    float s = 0.f;
    for (int c0 = 0; c0 < C_; c0 += 8) {
        float e = 0.f;
        #pragma unroll
        for (int j = 0; j < 8; ++j) e += bf2f(pp[(size_t)(c0 + j) * HWI]);
        s += e;
    }
    sr[qidx] = 1.0f / s;
}

// ---------------------------------------------------------------------------
// pvP: out1 = (P .* sr) @ g1 via 1-term fp16 MFMA. P*sr in [0,1] -> fp16.
// grid (C_, B_), 16 KB LDS. out1 fp16.
// ---------------------------------------------------------------------------
__global__ __launch_bounds__(256)
void pvP_k(const unsigned short* __restrict__ P, const float* __restrict__ sr,
           const unsigned short* __restrict__ g1, unsigned short* __restrict__ out1)
{
    __shared__ short pa[64 * 64], gb[64 * 64];

    const int tid = threadIdx.x, lane = tid & 63, wv = tid >> 6;
    const int c = blockIdx.x, b = blockIdx.y;
    const size_t base = ((size_t)b * C_ + c) * HWI;

    const int r = tid >> 2, q8 = (tid & 3) * 2;
    {   // A = P' = P * sr  (fp16)  [h][g]
        const size_t g0 = base + r * 64 + q8 * 8;
        const float* srp = sr + (size_t)b * HWI + r * 64 + q8 * 8;
        short8 p0 = *(const short8*)(P + g0), p1 = *(const short8*)(P + g0 + 8);
        short8 w0, w1;
        #pragma unroll
        for (int j = 0; j < 8; ++j) {
            w0[j] = (short)f2h(bf2f((unsigned short)p0[j]) * srp[j]);
            w1[j] = (short)f2h(bf2f((unsigned short)p1[j]) * srp[8 + j]);
        }
        const int c0 = (q8 ^ (r & 7)) * 8, c1 = ((q8 + 1) ^ (r & 7)) * 8;
        *(short8*)&pa[r * 64 + c0] = w0;
        *(short8*)&pa[r * 64 + c1] = w1;
    }
    {   // B = g1^T : gb[w][g]  (fp16 bits moved)
        const int w = tid & 63, kq = tid >> 6;
        short8 t0, t1;
        #pragma unroll
        for (int j = 0; j < 8; ++j) t0[j] = (short)g1[base + (size_t)(kq * 16 + j) * 64 + w];
        #pragma unroll
        for (int j = 0; j < 8; ++j) t1[j] = (short)g1[base + (size_t)(kq * 16 + 8 + j) * 64 + w];
        const int c0 = ((kq * 2) ^ (w & 7)) * 8, c1 = ((kq * 2 + 1) ^ (w & 7)) * 8;
        *(short8*)&gb[w * 64 + c0] = t0;
        *(short8*)&gb[w * 64 + c1] = t1;
    }
    __syncthreads();

    f32x4 acc[4] = {};
    const int m = wv * 16 + (lane & 15);
    #pragma unroll
    for (int s = 0; s < 2; ++s) {
        const int k8 = s * 4 + (lane >> 4);
        half8 aa = *(const half8*)&pa[m * 64 + (k8 ^ (m & 7)) * 8];
        #pragma unroll
        for (int nf = 0; nf < 4; ++nf) {
            const int n = nf * 16 + (lane & 15);
            half8 bb = *(const half8*)&gb[n * 64 + (k8 ^ (n & 7)) * 8];
            acc[nf] = MFMAH(aa, bb, acc[nf]);
        }
    }
    __syncthreads();

    short* ot = pa;
    #pragma unroll
    for (int nf = 0; nf < 4; ++nf)
        #pragma unroll
        for (int rr = 0; rr < 4; ++rr) {
            const int h = wv * 16 + (lane >> 4) * 4 + rr;
            const int w = nf * 16 + (lane & 15);
            ot[h * 64 + (((w >> 3) ^ (h & 7)) * 8) + (w & 7)] = (short)f2h(acc[nf][rr]);
        }
    __syncthreads();
    {
        const size_t g0 = base + r * 64 + q8 * 8;
        const int c0 = (q8 ^ (r & 7)) * 8, c1 = ((q8 + 1) ^ (r & 7)) * 8;
        *(short8*)(out1 + g0)     = *(const short8*)&ot[r * 64 + c0];
        *(short8*)(out1 + g0 + 8) = *(const short8*)&ot[r * 64 + c1];
    }
}

// ---------------------------------------------------------------------------
// fallback middle kernels (small-ws path)
// ---------------------------------------------------------------------------
__global__ __launch_bounds__(256)
void zgemm_k(const float* f1, const float* __restrict__ f2, float* z)
{
    __shared__ float aT[64][64];
    __shared__ float bT[64][64];

    const int tid = threadIdx.x;
    const int c = blockIdx.x, b = blockIdx.y;
    const size_t base = ((size_t)b * C_ + c) * HWI;

    const int r = tid >> 2;
    const int q = (tid & 3) << 4;
    {
        const float* pa = f1 + base + (size_t)r * HDIM + q;
        const float* pb = f2 + base + (size_t)r * HDIM + q;
        float4 v0 = *(const float4*)(pa + 0);
        float4 v1 = *(const float4*)(pa + 4);
        float4 v2 = *(const float4*)(pa + 8);
        float4 v3 = *(const float4*)(pa + 12);
        float4 u0 = *(const float4*)(pb + 0);
        float4 u1 = *(const float4*)(pb + 4);
        float4 u2 = *(const float4*)(pb + 8);
        float4 u3 = *(const float4*)(pb + 12);
        float ta[16] = {v0.x,v0.y,v0.z,v0.w, v1.x,v1.y,v1.z,v1.w,
                        v2.x,v2.y,v2.z,v2.w, v3.x,v3.y,v3.z,v3.w};
        float tb[16] = {u0.x,u0.y,u0.z,u0.w, u1.x,u1.y,u1.z,u1.w,
                        u2.x,u2.y,u2.z,u2.w, u3.x,u3.y,u3.z,u3.w};
        #pragma unroll
        for (int j = 0; j < 16; ++j) { aT[q + j][r] = ta[j]; bT[q + j][r] = tb[j]; }
    }
    __syncthreads();

    const int tx = tid & 15, ty = tid >> 4;
    float acc[4][4] = {};
    #pragma unroll 8
    for (int w = 0; w < 64; ++w) {
        float4 a = *(const float4*)&aT[w][ty * 4];
        float4 g = *(const float4*)&bT[w][tx * 4];
        float av[4] = {a.x, a.y, a.z, a.w};
        float gv[4] = {g.x, g.y, g.z, g.w};
        #pragma unroll
        for (int i = 0; i < 4; ++i)
            #pragma unroll
            for (int j = 0; j < 4; ++j)
                acc[i][j] += av[i] * gv[j];
    }

    float* zb = z + base;
    #pragma unroll
    for (int i = 0; i < 4; ++i)
        *(float4*)&zb[(size_t)(ty * 4 + i) * HDIM + tx * 4] =
            make_float4(acc[i][0], acc[i][1], acc[i][2], acc[i][3]);
}

__global__ __launch_bounds__(256)
void stats_k(const float* __restrict__ z, float* __restrict__ sr)
{
    const int qidx = blockIdx.x * 256 + threadIdx.x;
    const int b = qidx >> 12, p = qidx & 4095;
    const float* zp = z + (size_t)b * C_ * HWI + p;
    float s = 0.f;
    for (int c0 = 0; c0 < C_; c0 += 8) {
        float v[8];
        #pragma unroll
        for (int j = 0; j < 8; ++j) v[j] = zp[(size_t)(c0 + j) * HWI];
        float e = 0.f;
        #pragma unroll
        for (int j = 0; j < 8; ++j) e += __expf(v[j] - SHIFT);
        s += e;
    }
    sr[qidx] = 1.0f / s;
}

__global__ __launch_bounds__(256)
void pvgemm_k(const float* __restrict__ z, const float* __restrict__ sr,
              const unsigned short* __restrict__ g1,
              unsigned short* __restrict__ out1)
{
    __shared__ float pT[64][64];
    __shared__ float gl[64][64];

    const int tid = threadIdx.x;
    const int c = blockIdx.x, b = blockIdx.y;
    const size_t base = ((size_t)b * C_ + c) * HWI;

    const int r = tid >> 2;
    const int q = (tid & 3) << 4;
    {
        const float* zp = z  + base + (size_t)r * HDIM + q;
        const float* rp = sr + (size_t)b * HWI + (size_t)r * HDIM + q;
        const unsigned short* gp = g1 + base + (size_t)r * HDIM + q;
        float pv[16], gv[16];
        #pragma unroll
        for (int j = 0; j < 4; ++j) {
            float4 zv = *(const float4*)(zp + j * 4);
            float4 rv = *(const float4*)(rp + j * 4);
            pv[j*4+0] = __expf(zv.x - SHIFT) * rv.x;
            pv[j*4+1] = __expf(zv.y - SHIFT) * rv.y;
            pv[j*4+2] = __expf(zv.z - SHIFT) * rv.z;
            pv[j*4+3] = __expf(zv.w - SHIFT) * rv.w;
        }
        short8 ga = *(const short8*)(gp + 0);
        short8 gb = *(const short8*)(gp + 8);
        #pragma unroll
        for (int j = 0; j < 8; ++j) { gv[j] = h2f((unsigned short)ga[j]); gv[8 + j] = h2f((unsigned short)gb[j]); }
        #pragma unroll
        for (int j = 0; j < 16; ++j) { pT[q + j][r] = pv[j]; gl[r][q + j] = gv[j]; }
    }
    __syncthreads();

    const int tx = tid & 15, ty = tid >> 4;
    float acc[4][4] = {};
    #pragma unroll 8
    for (int g = 0; g < 64; ++g) {
        float4 a = *(const float4*)&pT[g][ty * 4];
        float4 vv4 = *(const float4*)&gl[g][tx * 4];
        float av[4] = {a.x, a.y, a.z, a.w};
        float vv[4] = {vv4.x, vv4.y, vv4.z, vv4.w};
        #pragma unroll
        for (int i = 0; i < 4; ++i)
            #pragma unroll
            for (int j = 0; j < 4; ++j)
                acc[i][j] += av[i] * vv[j];
    }

    unsigned short* ob = out1 + base;
    #pragma unroll
    for (int i = 0; i < 4; ++i) {
        s4v w;
        #pragma unroll
        for (int j = 0; j < 4; ++j) w[j] = (short)f2h(acc[i][j]);
        *(s4v*)&ob[(size_t)(ty * 4 + i) * HDIM + tx * 4] = w;
    }
}

// ---------------------------------------------------------------------------
extern "C" void kernel_launch(void* const* d_in, const int* in_sizes, int n_in,
                              void* d_out, int out_size, void* d_ws, size_t ws_size,
                              hipStream_t stream)
{
    (void)in_sizes; (void)n_in; (void)out_size;
    const float* x  = (const float*)d_in[0];
    const float* wq = (const float*)d_in[1];
    const float* bq = (const float*)d_in[2];
    const float* wv = (const float*)d_in[3];
    const float* bv = (const float*)d_in[4];
    const float* wk = (const float*)d_in[5];
    const float* bk = (const float*)d_in[6];
    const float* wy = (const float*)d_in[7];
    const float* by = (const float*)d_in[8];
    float* out = (float*)d_out;

    const size_t N  = (size_t)B_ * C_ * HWI;   // 33,554,432
    const size_t NS = (size_t)B_ * HWI;        // 131,072

    char* wsb = (char*)d_ws;
    short* wsp = (short*)wsb;
    const size_t wbytes = 8 * (size_t)NW * sizeof(short);   // 1 MB
    char* fb = wsb + wbytes;

    dim3 blk(256);
    hipLaunchKernelGGL(wsplit4_k, dim3(32, 4), blk, 0, stream, wq, wv, wk, wy, wsp);
    const short* wqvk = wsp;
    const short* why  = wsp + 6 * NW;
    const short* wly  = wsp + 7 * NW;

    dim3 cgrid(HWI / 64, B_);     // 2048 blocks
    dim3 zgrid(C_, B_);           // 8192 blocks
    dim3 sgrid((unsigned)(NS / 256));

    const bool bigws = ws_size >= wbytes + 8 * N + 4 * NS;

    if (bigws) {
        // ws: f1 | f2 | g1 | P  (2N bytes each, fp16/fp16/fp16/bf16) | sr
        unsigned short* f1  = (unsigned short*)fb;
        unsigned short* f2  = (unsigned short*)(fb + 2 * N);
        unsigned short* g1  = (unsigned short*)(fb + 4 * N);
        unsigned short* P   = (unsigned short*)(fb + 6 * N);
        float*          sr  = (float*)(fb + 8 * N);
        unsigned short* o1  = f1;   // reuse (f1 dead after zgemmP)

        hipLaunchKernelGGL(convQVK_k, cgrid, blk, 0, stream,
                           x, wqvk, bq, bv, bk, f1, f2, g1);
        hipLaunchKernelGGL(zgemmP_k, zgrid, blk, 0, stream, f1, f2, P);
        hipLaunchKernelGGL(statsP_k, sgrid, blk, 0, stream, P, sr);
        hipLaunchKernelGGL(pvP_k,    zgrid, blk, 0, stream, P, sr, g1, o1);
        hipLaunchKernelGGL(convY_k,  cgrid, blk, 0, stream, o1, x, why, wly, by, out);
    } else {
        // fallback small-ws path
        float*          f2  = (float*)fb;
        unsigned short* g1b = (unsigned short*)fb;
        unsigned short* o1b = (unsigned short*)fb + N;
        float*          sr  = (float*)(fb + 4 * N);
        hipLaunchKernelGGL((convN_k<2, false>), cgrid, blk, 0, stream,
                           x, wqvk, bq, bv, (const float*)0, out, f2, (void*)0);
        hipLaunchKernelGGL(zgemm_k,  zgrid, blk, 0, stream, out, f2, out);
        hipLaunchKernelGGL(stats_k,  sgrid, blk, 0, stream, out, sr);
        hipLaunchKernelGGL((convN_k<1, true>), cgrid, blk, 0, stream,
                           x, wqvk + 4 * (size_t)NW, bk, (const float*)0, (const float*)0,
                           g1b, (void*)0, (void*)0);
        hipLaunchKernelGGL(pvgemm_k, zgrid, blk, 0, stream, out, sr, g1b, o1b);
        hipLaunchKernelGGL(convY_k,  cgrid, blk, 0, stream, o1b, x, why, wly, by, out);
    }
}

// Round 12
// 329.006 us; speedup vs baseline: 1.6962x; 1.0141x over previous
//
#include <hip/hip_runtime.h>
#include <hip/hip_bf16.h>

#define B_    32
#define C_    256
#define HWI   4096   // 64*64
#define NW    65536  // elems per weight matrix (256x256)
#define SHIFT 20.0f  // fixed softmax shift

typedef short short8 __attribute__((ext_vector_type(8)));
typedef short s4v    __attribute__((ext_vector_type(4)));
typedef float f32x4  __attribute__((ext_vector_type(4)));
typedef _Float16 half8 __attribute__((ext_vector_type(8)));

#define MFMAH(a, b, c) __builtin_amdgcn_mfma_f32_16x16x32_f16(a, b, c, 0, 0, 0)

// fp16 helpers (RNE casts)
__device__ __forceinline__ unsigned short f2h(float x) {
    _Float16 t = (_Float16)x;
    return __builtin_bit_cast(unsigned short, t);
}
__device__ __forceinline__ float h2f(unsigned short b) {
    return (float)__builtin_bit_cast(_Float16, b);
}
// bf16 (for P only — needs > fp16 range)
__device__ __forceinline__ unsigned short f2bf(float x) {
    __hip_bfloat16 t = __float2bfloat16(x);
    return *reinterpret_cast<unsigned short*>(&t);
}
__device__ __forceinline__ float bf2f(unsigned short b) {
    return __uint_as_float((unsigned)b << 16);
}

// ---------------------------------------------------------------------------
// Convert ALL 4 weight matrices fp32 -> SINGLE fp16, MFMA-fragment-linear:
// flat = (o>>4)*4096 + (k>>3)*128 + (o&15)*8 + (k&7). grid (32, 4)
// (1-term conv error budget: W-quant 2.4e-4 + x-quant 2.4e-4 + f-storage
//  2.4e-4 RSS = 4.2e-4 rel, vs bf16-P storage 2e-3 rel which dominates.)
// ---------------------------------------------------------------------------
__global__ __launch_bounds__(256)
void wsingle4_k(const float* __restrict__ w0, const float* __restrict__ w1,
                const float* __restrict__ w2, const float* __restrict__ w3,
                short* __restrict__ dst)
{
    const int m = blockIdx.y;
    const float* w = (m == 0) ? w0 : (m == 1) ? w1 : (m == 2) ? w2 : w3;
    short* wd = dst + (size_t)m * NW;

    const int g  = blockIdx.x * 256 + threadIdx.x;
    const int o  = g >> 5, k8 = g & 31;
    const float* src = w + o * 256 + k8 * 8;
    const int d = (o >> 4) * 4096 + k8 * 128 + (o & 15) * 8;
    short8 h8;
    #pragma unroll
    for (int j = 0; j < 8; ++j) h8[j] = (short)f2h(src[j]);
    *(short8*)(wd + d) = h8;
}

// ---------------------------------------------------------------------------
// conv building blocks — single-fp16 x in LDS (32 KB), 1-term MFMA
// ---------------------------------------------------------------------------
__device__ __forceinline__ void stage_load(const float* __restrict__ inb,
                                           int half, int sp, int kq, float* v)
{
    #pragma unroll
    for (int r = 0; r < 4; ++r) {
        const int k8 = half * 16 + r * 4 + kq;
        const float* gx = inb + (size_t)(k8 * 8) * HWI + sp;
        #pragma unroll
        for (int j = 0; j < 8; ++j) v[r * 8 + j] = gx[(size_t)j * HWI];
    }
}

__device__ __forceinline__ void stage_write(int half, int sp, int kq,
        const float* v, short (*xs)[256])
{
    #pragma unroll
    for (int r = 0; r < 4; ++r) {
        const int k8 = half * 16 + r * 4 + kq;
        short8 h8;
        #pragma unroll
        for (int j = 0; j < 8; ++j) h8[j] = (short)f2h(v[r * 8 + j]);
        const int ch = (k8 ^ (sp & 7)) * 8;   // XOR stays within half's chunk range
        *(short8*)&xs[sp][ch] = h8;
    }
}

__device__ __forceinline__ void conv_step1(int s, int lane, int o16b,
        const short* __restrict__ w, const short (*xs)[256], f32x4 acc[4][4])
{
    const int k8 = s * 4 + (lane >> 4);
    half8 a[4], bq[4];
    #pragma unroll
    for (int i = 0; i < 4; ++i)
        a[i] = *(const half8*)(w + ((o16b + i) * 32 + k8) * 128 + (lane & 15) * 8);
    #pragma unroll
    for (int f = 0; f < 4; ++f) {
        const int pr = f * 16 + (lane & 15);
        bq[f] = *(const half8*)&xs[pr][(k8 ^ (pr & 7)) * 8];
    }
    __builtin_amdgcn_s_setprio(1);
    #pragma unroll
    for (int i = 0; i < 4; ++i)
        #pragma unroll
        for (int f = 0; f < 4; ++f)
            acc[i][f] = MFMAH(a[i], bq[f], acc[i][f]);
    __builtin_amdgcn_s_setprio(0);
}

__device__ __forceinline__ void conv_epi_h16(const f32x4 acc[4][4],
        const float* __restrict__ bias, unsigned short* __restrict__ ob,
        int p0, int wv, int lane)
{
    const int pl = p0 + (lane & 15);
    #pragma unroll
    for (int i = 0; i < 4; ++i)
        #pragma unroll
        for (int r = 0; r < 4; ++r) {
            const int o = wv * 64 + i * 16 + (lane >> 4) * 4 + r;
            const float bz = bias[o];
            #pragma unroll
            for (int f = 0; f < 4; ++f)
                ob[(size_t)o * HWI + pl + f * 16] = f2h(acc[i][f][r] + bz);
        }
}

// ---------------------------------------------------------------------------
// Fused q,v,k convs (fp32 in, 1-term fp16 MFMA). f1,f2,g1 out single fp16.
// 32 KB LDS, target 4 blocks/CU. XCD-chunked swizzle, split-stage pipeline.
// grid: (HWI/64, B_)
// ---------------------------------------------------------------------------
__global__ __launch_bounds__(256, 4)
void convQVK_k(const float* __restrict__ in, const short* __restrict__ wb,
               const float* __restrict__ b0, const float* __restrict__ b1,
               const float* __restrict__ b2,
               unsigned short* __restrict__ f1, unsigned short* __restrict__ f2,
               unsigned short* __restrict__ g1)
{
    __shared__ short xs[64][256];   // 32 KB, fp16 [p][k], chunk-XOR swizzle

    const int tid  = threadIdx.x;
    const int lane = tid & 63;
    const int wv   = tid >> 6;

    const int id    = blockIdx.y * gridDim.x + blockIdx.x;
    const int chunk = (gridDim.x * gridDim.y) >> 3;
    const int nid   = (id & 7) * chunk + (id >> 3);
    const int p0    = (nid & 63) * 64;
    const int b     = nid >> 6;

    const float* inb = in + (size_t)b * C_ * HWI + p0;
    const int sp = tid & 63, kq = tid >> 6;

    float v[32];
    stage_load(inb, 0, sp, kq, v);
    stage_write(0, sp, kq, v, xs);
    __syncthreads();

    const int o16b = wv * 4;
    const size_t obase = (size_t)b * C_ * HWI;

    // conv0 (q -> f1) with split-stage overlap
    stage_load(inb, 1, sp, kq, v);
    f32x4 acc[4][4] = {};
    #pragma unroll
    for (int s = 0; s < 4; ++s)
        conv_step1(s, lane, o16b, wb, xs, acc);
    stage_write(1, sp, kq, v, xs);
    __syncthreads();
    #pragma unroll
    for (int s = 4; s < 8; ++s)
        conv_step1(s, lane, o16b, wb, xs, acc);
    conv_epi_h16(acc, b0, f1 + obase, p0, wv, lane);

    // conv1 (v -> f2)
    {
        f32x4 acc2[4][4] = {};
        #pragma unroll 2
        for (int s = 0; s < 8; ++s)
            conv_step1(s, lane, o16b, wb + NW, xs, acc2);
        conv_epi_h16(acc2, b1, f2 + obase, p0, wv, lane);
    }

    // conv2 (k -> g1)
    {
        f32x4 acc3[4][4] = {};
        #pragma unroll 2
        for (int s = 0; s < 8; ++s)
            conv_step1(s, lane, o16b, wb + 2 * (size_t)NW, xs, acc3);
        conv_epi_h16(acc3, b2, g1 + obase, p0, wv, lane);
    }
}

// ---------------------------------------------------------------------------
// Final conv: fp16 input, 1-term fp16 MFMA, +bias +residual -> fp32. 32 KB.
// grid: (HWI/64, B_)
// ---------------------------------------------------------------------------
__global__ __launch_bounds__(256, 4)
void convY_k(const unsigned short* __restrict__ in, const float* __restrict__ res,
             const short* __restrict__ w, const float* __restrict__ bias,
             float* __restrict__ out)
{
    __shared__ short ys[64][256];   // 32 KB

    const int tid  = threadIdx.x;
    const int lane = tid & 63;
    const int wv   = tid >> 6;

    const int id    = blockIdx.y * gridDim.x + blockIdx.x;
    const int chunk = (gridDim.x * gridDim.y) >> 3;
    const int nid   = (id & 7) * chunk + (id >> 3);
    const int p0    = (nid & 63) * 64;
    const int b     = nid >> 6;

    const unsigned short* inb = in + (size_t)b * C_ * HWI + p0;
    const int sp = tid & 63, kq = tid >> 6;

    unsigned short uv[32];

    // stage half 0
    #pragma unroll
    for (int r = 0; r < 4; ++r) {
        const int k8 = r * 4 + kq;
        #pragma unroll
        for (int j = 0; j < 8; ++j) uv[r * 8 + j] = inb[(size_t)(k8 * 8 + j) * HWI + sp];
    }
    #pragma unroll
    for (int r = 0; r < 4; ++r) {
        const int k8 = r * 4 + kq;
        short8 v8;
        #pragma unroll
        for (int j = 0; j < 8; ++j) v8[j] = (short)uv[r * 8 + j];
        *(short8*)&ys[sp][(k8 ^ (sp & 7)) * 8] = v8;
    }
    __syncthreads();

    // issue half-1 loads
    #pragma unroll
    for (int r = 0; r < 4; ++r) {
        const int k8 = 16 + r * 4 + kq;
        #pragma unroll
        for (int j = 0; j < 8; ++j) uv[r * 8 + j] = inb[(size_t)(k8 * 8 + j) * HWI + sp];
    }

    const int o16b = wv * 4;
    f32x4 acc[4][4] = {};

    #pragma unroll
    for (int s = 0; s < 4; ++s)
        conv_step1(s, lane, o16b, w, ys, acc);

    #pragma unroll
    for (int r = 0; r < 4; ++r) {
        const int k8 = 16 + r * 4 + kq;
        short8 v8;
        #pragma unroll
        for (int j = 0; j < 8; ++j) v8[j] = (short)uv[r * 8 + j];
        *(short8*)&ys[sp][(k8 ^ (sp & 7)) * 8] = v8;
    }
    __syncthreads();

    #pragma unroll
    for (int s = 4; s < 8; ++s)
        conv_step1(s, lane, o16b, w, ys, acc);

    float* ob = out + (size_t)b * C_ * HWI;
    const float* rb = res + (size_t)b * C_ * HWI;
    const int pl = p0 + (lane & 15);
    #pragma unroll
    for (int i = 0; i < 4; ++i)
        #pragma unroll
        for (int r = 0; r < 4; ++r) {
            const int o = wv * 64 + i * 16 + (lane >> 4) * 4 + r;
            const float bz = bias[o];
            #pragma unroll
            for (int f = 0; f < 4; ++f) {
                const size_t off = (size_t)o * HWI + pl + f * 16;
                ob[off] = acc[i][f][r] + bz + rb[off];
            }
        }
}

// ---------------------------------------------------------------------------
// zgemmP: per-(b,c) z = f1 @ f2^T via 1-term fp16 MFMA, fused exp epilogue
// -> P = e^(z-SHIFT) bf16 (range!), LDS-transposed coalesced store.
// grid (C_, B_), 256 thr (4 waves), 16 KB LDS.
// ---------------------------------------------------------------------------
__global__ __launch_bounds__(256)
void zgemmP_k(const unsigned short* __restrict__ f1,
              const unsigned short* __restrict__ f2,
              unsigned short* __restrict__ P)
{
    __shared__ short am[64 * 64], bm[64 * 64];   // 16 KB

    const int tid = threadIdx.x, lane = tid & 63, wv = tid >> 6;
    const int c = blockIdx.x, b = blockIdx.y;
    const size_t base = ((size_t)b * C_ + c) * HWI;

    const int r = tid >> 2, q8 = (tid & 3) * 2;
    {
        const size_t g0 = base + r * 64 + q8 * 8;
        short8 v0 = *(const short8*)(f1 + g0), v1 = *(const short8*)(f1 + g0 + 8);
        short8 u0 = *(const short8*)(f2 + g0), u1 = *(const short8*)(f2 + g0 + 8);
        const int c0 = (q8 ^ (r & 7)) * 8, c1 = ((q8 + 1) ^ (r & 7)) * 8;
        *(short8*)&am[r * 64 + c0] = v0;  *(short8*)&am[r * 64 + c1] = v1;
        *(short8*)&bm[r * 64 + c0] = u0;  *(short8*)&bm[r * 64 + c1] = u1;
    }
    __syncthreads();

    f32x4 acc[4] = {};
    const int m = wv * 16 + (lane & 15);
    #pragma unroll
    for (int s = 0; s < 2; ++s) {
        const int k8 = s * 4 + (lane >> 4);
        half8 a = *(const half8*)&am[m * 64 + (k8 ^ (m & 7)) * 8];
        #pragma unroll
        for (int nf = 0; nf < 4; ++nf) {
            const int n = nf * 16 + (lane & 15);
            half8 bb = *(const half8*)&bm[n * 64 + (k8 ^ (n & 7)) * 8];
            acc[nf] = MFMAH(a, bb, acc[nf]);
        }
    }
    __syncthreads();   // all frag reads done; reuse am as transpose buffer

    short* pt = am;
    #pragma unroll
    for (int nf = 0; nf < 4; ++nf)
        #pragma unroll
        for (int rr = 0; rr < 4; ++rr) {
            const int h = wv * 16 + (lane >> 4) * 4 + rr;
            const int g = nf * 16 + (lane & 15);
            const float pv = __expf(acc[nf][rr] - SHIFT);
            pt[h * 64 + (((g >> 3) ^ (h & 7)) * 8) + (g & 7)] = (short)f2bf(pv);
        }
    __syncthreads();
    {
        const size_t g0 = base + r * 64 + q8 * 8;
        const int c0 = (q8 ^ (r & 7)) * 8, c1 = ((q8 + 1) ^ (r & 7)) * 8;
        *(short8*)(P + g0)     = *(const short8*)&pt[r * 64 + c0];
        *(short8*)(P + g0 + 8) = *(const short8*)&pt[r * 64 + c1];
    }
}

// ---------------------------------------------------------------------------
// statsP: sr[b,p] = 1 / sum_c P[b,c,p]   (P bf16)
// ---------------------------------------------------------------------------
__global__ __launch_bounds__(256)
void statsP_k(const unsigned short* __restrict__ P, float* __restrict__ sr)
{
    const int qidx = blockIdx.x * 256 + threadIdx.x;
    const int b = qidx >> 12, p = qidx & 4095;
    const unsigned short* pp = P + (size_t)b * C_ * HWI + p;
    float s = 0.f;
    for (int c0 = 0; c0 < C_; c0 += 8) {
        float e = 0.f;
        #pragma unroll
        for (int j = 0; j < 8; ++j) e += bf2f(pp[(size_t)(c0 + j) * HWI]);
        s += e;
    }
    sr[qidx] = 1.0f / s;
}

// ---------------------------------------------------------------------------
// pvP: out1 = (P .* sr) @ g1 via 1-term fp16 MFMA. P*sr in [0,1] -> fp16.
// grid (C_, B_), 16 KB LDS. out1 fp16.
// ---------------------------------------------------------------------------
__global__ __launch_bounds__(256)
void pvP_k(const unsigned short* __restrict__ P, const float* __restrict__ sr,
           const unsigned short* __restrict__ g1, unsigned short* __restrict__ out1)
{
    __shared__ short pa[64 * 64], gb[64 * 64];

    const int tid = threadIdx.x, lane = tid & 63, wv = tid >> 6;
    const int c = blockIdx.x, b = blockIdx.y;
    const size_t base = ((size_t)b * C_ + c) * HWI;

    const int r = tid >> 2, q8 = (tid & 3) * 2;
    {   // A = P' = P * sr  (fp16)  [h][g]
        const size_t g0 = base + r * 64 + q8 * 8;
        const float* srp = sr + (size_t)b * HWI + r * 64 + q8 * 8;
        short8 p0 = *(const short8*)(P + g0), p1 = *(const short8*)(P + g0 + 8);
        short8 w0, w1;
        #pragma unroll
        for (int j = 0; j < 8; ++j) {
            w0[j] = (short)f2h(bf2f((unsigned short)p0[j]) * srp[j]);
            w1[j] = (short)f2h(bf2f((unsigned short)p1[j]) * srp[8 + j]);
        }
        const int c0 = (q8 ^ (r & 7)) * 8, c1 = ((q8 + 1) ^ (r & 7)) * 8;
        *(short8*)&pa[r * 64 + c0] = w0;
        *(short8*)&pa[r * 64 + c1] = w1;
    }
    {   // B = g1^T : gb[w][g]
        const int w = tid & 63, kq = tid >> 6;
        short8 t0, t1;
        #pragma unroll
        for (int j = 0; j < 8; ++j) t0[j] = (short)g1[base + (size_t)(kq * 16 + j) * 64 + w];
        #pragma unroll
        for (int j = 0; j < 8; ++j) t1[j] = (short)g1[base + (size_t)(kq * 16 + 8 + j) * 64 + w];
        const int c0 = ((kq * 2) ^ (w & 7)) * 8, c1 = ((kq * 2 + 1) ^ (w & 7)) * 8;
        *(short8*)&gb[w * 64 + c0] = t0;
        *(short8*)&gb[w * 64 + c1] = t1;
    }
    __syncthreads();

    f32x4 acc[4] = {};
    const int m = wv * 16 + (lane & 15);
    #pragma unroll
    for (int s = 0; s < 2; ++s) {
        const int k8 = s * 4 + (lane >> 4);
        half8 aa = *(const half8*)&pa[m * 64 + (k8 ^ (m & 7)) * 8];
        #pragma unroll
        for (int nf = 0; nf < 4; ++nf) {
            const int n = nf * 16 + (lane & 15);
            half8 bb = *(const half8*)&gb[n * 64 + (k8 ^ (n & 7)) * 8];
            acc[nf] = MFMAH(aa, bb, acc[nf]);
        }
    }
    __syncthreads();

    short* ot = pa;
    #pragma unroll
    for (int nf = 0; nf < 4; ++nf)
        #pragma unroll
        for (int rr = 0; rr < 4; ++rr) {
            const int h = wv * 16 + (lane >> 4) * 4 + rr;
            const int w = nf * 16 + (lane & 15);
            ot[h * 64 + (((w >> 3) ^ (h & 7)) * 8) + (w & 7)] = (short)f2h(acc[nf][rr]);
        }
    __syncthreads();
    {
        const size_t g0 = base + r * 64 + q8 * 8;
        const int c0 = (q8 ^ (r & 7)) * 8, c1 = ((q8 + 1) ^ (r & 7)) * 8;
        *(short8*)(out1 + g0)     = *(const short8*)&ot[r * 64 + c0];
        *(short8*)(out1 + g0 + 8) = *(const short8*)&ot[r * 64 + c1];
    }
}

// ---------------------------------------------------------------------------
extern "C" void kernel_launch(void* const* d_in, const int* in_sizes, int n_in,
                              void* d_out, int out_size, void* d_ws, size_t ws_size,
                              hipStream_t stream)
{
    (void)in_sizes; (void)n_in; (void)out_size;
    const float* x  = (const float*)d_in[0];
    const float* wq = (const float*)d_in[1];
    const float* bq = (const float*)d_in[2];
    const float* wv = (const float*)d_in[3];
    const float* bv = (const float*)d_in[4];
    const float* wk = (const float*)d_in[5];
    const float* bk = (const float*)d_in[6];
    const float* wy = (const float*)d_in[7];
    const float* by = (const float*)d_in[8];
    float* out = (float*)d_out;

    const size_t N  = (size_t)B_ * C_ * HWI;   // 33,554,432
    const size_t NS = (size_t)B_ * HWI;        // 131,072

    char* wsb = (char*)d_ws;
    short* wsp = (short*)wsb;
    const size_t wbytes = 4 * (size_t)NW * sizeof(short);   // 512 KB
    char* fb = wsb + wbytes;

    dim3 blk(256);
    hipLaunchKernelGGL(wsingle4_k, dim3(32, 4), blk, 0, stream, wq, wv, wk, wy, wsp);
    const short* wqvk = wsp;                 // q,v,k (3 x NW)
    const short* wyp  = wsp + 3 * (size_t)NW;

    dim3 cgrid(HWI / 64, B_);     // 2048 blocks
    dim3 zgrid(C_, B_);           // 8192 blocks
    dim3 sgrid((unsigned)(NS / 256));

    // Layout A (ws >= 0.5MB + 8N + 4NS bytes): everything in ws (proven path)
    // Layout B (ws >= 0.5MB + 4N + 4NS bytes): f2,P live in d_out (dead until convY)
    const bool bigA = ws_size >= wbytes + 8 * N + 4 * NS;

    unsigned short *f1, *f2, *g1, *P, *o1;
    float* sr;
    if (bigA) {
        f1 = (unsigned short*)fb;
        f2 = (unsigned short*)(fb + 2 * N);
        g1 = (unsigned short*)(fb + 4 * N);
        P  = (unsigned short*)(fb + 6 * N);
        sr = (float*)(fb + 8 * N);
    } else {
        f1 = (unsigned short*)fb;
        g1 = (unsigned short*)(fb + 2 * N);
        sr = (float*)(fb + 4 * N);
        f2 = (unsigned short*)d_out;          // d_out = 4N bytes total
        P  = (unsigned short*)d_out + N;
    }
    o1 = f1;   // reuse (f1 dead after zgemmP)

    hipLaunchKernelGGL(convQVK_k, cgrid, blk, 0, stream,
                       x, wqvk, bq, bv, bk, f1, f2, g1);
    hipLaunchKernelGGL(zgemmP_k, zgrid, blk, 0, stream, f1, f2, P);
    hipLaunchKernelGGL(statsP_k, sgrid, blk, 0, stream, P, sr);
    hipLaunchKernelGGL(pvP_k,    zgrid, blk, 0, stream, P, sr, g1, o1);
    hipLaunchKernelGGL(convY_k,  cgrid, blk, 0, stream, o1, x, wyp, by, out);
}